// Round 11
// baseline (2452.680 us; speedup 1.0000x reference)
//
#include <hip/hip_runtime.h>

// ---------------------------------------------------------------------------
// Fused MHA: qkv = x@Wqkv+b ; causal attention ; out = attn@Wproj+b
// B=4, T=2048, C=2048, H=16, D=128. fp32 in/out, bf16 MFMA internally.
// (Round 10 resubmit — container died on infra, not kernel; code unchanged.)
// ---------------------------------------------------------------------------

typedef __bf16 bf16;
typedef __bf16 bf16x8 __attribute__((ext_vector_type(8)));
typedef __bf16 bf16x4 __attribute__((ext_vector_type(4)));
typedef float f32x4 __attribute__((ext_vector_type(4)));

__device__ __forceinline__ void gload_lds16(const void* g, void* l) {
  __builtin_amdgcn_global_load_lds(
      (const __attribute__((address_space(1))) void*)g,
      (__attribute__((address_space(3))) void*)l, 16, 0, 0);
}

// ---------------------------------------------------------------------------
// cast fp32 -> bf16, 8 elems/thread
__global__ __launch_bounds__(256) void cast_f32_bf16(
    const float* __restrict__ in, bf16* __restrict__ out, int n8) {
  int i = blockIdx.x * 256 + threadIdx.x;
  if (i >= n8) return;
  const float4* p = (const float4*)in + (size_t)i * 2;
  float4 a = p[0], b = p[1];
  bf16x8 o8 = {(bf16)a.x, (bf16)a.y, (bf16)a.z, (bf16)a.w,
               (bf16)b.x, (bf16)b.y, (bf16)b.z, (bf16)b.w};
  *(bf16x8*)(out + (size_t)i * 8) = o8;
}

// ---------------------------------------------------------------------------
// W [R][C] fp32  ->  WT [C][R] bf16   (32x32 LDS tile transpose)
__global__ __launch_bounds__(256) void transpose_cast(
    const float* __restrict__ in, bf16* __restrict__ out, int R, int C) {
  __shared__ bf16 tile[32][33];
  const int r0 = blockIdx.y * 32, c0 = blockIdx.x * 32;
  const int tid = threadIdx.x;
  const int c = tid & 31, r = tid >> 5;
#pragma unroll
  for (int rr = r; rr < 32; rr += 8)
    tile[rr][c] = (bf16)in[(size_t)(r0 + rr) * C + c0 + c];
  __syncthreads();
  const int oc = tid >> 3;           // out row within tile (0..31)
  const int ok = (tid & 7) * 4;      // out col chunk
  bf16x4 v;
#pragma unroll
  for (int j = 0; j < 4; ++j) v[j] = tile[ok + j][oc];
  *(bf16x4*)&out[(size_t)(c0 + oc) * R + r0 + ok] = v;
}

// ---------------------------------------------------------------------------
// 256x256 GEMM, 2 BLOCKS/CU: C = A @ BT^T + bias.
// A [M][K] bf16 row-major, BT [N][K] bf16. 512 thr = 8 waves (2M x 4N).
// BK=32; LDS = ring-2 x (A 16KB + B 16KB) = 64 KiB -> 2 blocks/CU
// (__launch_bounds__(512,4) = 4 waves/SIMD). Rationale: R7-R9 showed all
// single-block schedules stuck at MfmaUtil 32% -- the CU's 8 waves share one
// barrier and oscillate in lockstep between LDS-phase and MFMA-phase. Two
// co-resident blocks have independent barriers: one block's MFMA burst fills
// the matrix pipe while the other stalls (m114 co-scheduling).
// Per K-tile t: vmcnt(0) [drains tile-t loads, issued one full compute phase
// ago] -> s_barrier [tile-t visible; buffer of t-1 vacated by all waves] ->
// STAGE(t+1) [flies under compute] -> COMPUTE(t) (12 ds_read + 32 MFMA,
// compiler-scheduled). 64B rows with byte-bit5 ^= row-bit3 swizzle applied
// both-sides (pre-XOR'd source col + XOR'd ds_read).
// EPI 0: scatter Q [BH][T][D], K [BH][T][D], V^T [BH][D][T]; EPI 1: fp32+bias.
template <int EPI>
__global__ __launch_bounds__(512, 4) void gemm256(
    const bf16* __restrict__ A, const bf16* __restrict__ BT,
    const float* __restrict__ bias, int M, int N, int K,
    float* __restrict__ outf, bf16* __restrict__ qb, bf16* __restrict__ kb,
    bf16* __restrict__ vtb) {
  __shared__ bf16 As[2][256 * 32];  // 32 KB ring
  __shared__ bf16 Bs[2][256 * 32];  // 32 KB ring
  const int tid = threadIdx.x;
  const int lane = tid & 63, w = tid >> 6;
  const int wm = w >> 2, wn = w & 3;
  const int lr = lane & 15, lg = lane >> 4;

  // bijective XCD swizzle (gridDim.x % 8 == 0 for both instantiations)
  const int nwg = gridDim.x, cpx = nwg >> 3;
  const int swz = (blockIdx.x & 7) * cpx + (blockIdx.x >> 3);
  const int ntx = N >> 8;  // tiles along N
  const int m0 = (swz / ntx) * 256, n0 = (swz % ntx) * 256;

  // stage K-tile kt (A 16KB + B 16KB) into ring buffer d: 4 gload_lds/thread.
  // dest linear; source col pre-XOR'd by row-bit3 (both-sides swizzle).
  auto STAGE = [&](int d, int kt) {
#pragma unroll
    for (int s = 0; s < 2; ++s) {
      const bf16* src = s ? BT : A;
      const int r0 = s ? n0 : m0;
      bf16* lb = s ? &Bs[d][0] : &As[d][0];
#pragma unroll
      for (int c = 0; c < 2; ++c) {
        const int chunk = w * 2 + c;                    // 0..15 (1KB chunks)
        const int row = chunk * 16 + (lane >> 2);       // 0..255
        const int col = ((lane & 3) * 8) ^ (((row >> 3) & 1) << 4);
        gload_lds16(src + (size_t)(r0 + row) * K + kt * 32 + col,
                    (char*)lb + chunk * 1024);
      }
    }
  };
  // fragment reads (swizzled): logical (row, lg*8..+7)
  auto LDA = [&](int d, int mi) -> bf16x8 {
    const int row = wm * 128 + mi * 16 + lr;
    return *(const bf16x8*)((const char*)&As[d][0] +
                            ((row * 64 + lg * 16) ^ ((lr >> 3) << 5)));
  };
  auto LDB = [&](int d, int ni) -> bf16x8 {
    const int row = wn * 64 + ni * 16 + lr;
    return *(const bf16x8*)((const char*)&Bs[d][0] +
                            ((row * 64 + lg * 16) ^ ((lr >> 3) << 5)));
  };

  f32x4 acc[8][4] = {};
  const int NT = K >> 5;  // BK=32

  STAGE(0, 0);  // prologue

  for (int t = 0; t < NT; ++t) {
    const int cur = t & 1;
    // tile t's loads were issued one full compute phase ago (except t=0)
    asm volatile("s_waitcnt vmcnt(0)" ::: "memory");
    __builtin_amdgcn_s_barrier();  // tile t visible; buf cur^1 vacated
    if (t + 1 < NT) STAGE(cur ^ 1, t + 1);  // flies under compute(t)

    __builtin_amdgcn_s_setprio(1);
    {
      bf16x8 af[8], bfr[4];
#pragma unroll
      for (int mi = 0; mi < 8; ++mi) af[mi] = LDA(cur, mi);
#pragma unroll
      for (int ni = 0; ni < 4; ++ni) bfr[ni] = LDB(cur, ni);
#pragma unroll
      for (int mi = 0; mi < 8; ++mi)
#pragma unroll
        for (int ni = 0; ni < 4; ++ni)
          acc[mi][ni] = __builtin_amdgcn_mfma_f32_16x16x32_bf16(
              af[mi], bfr[ni], acc[mi][ni], 0, 0, 0);
    }
    __builtin_amdgcn_s_setprio(0);
  }

  // epilogue: C/D layout col=lane&15, row=(lane>>4)*4+r  [m89/m91]
#pragma unroll
  for (int mi = 0; mi < 8; ++mi) {
    const int mbase = m0 + wm * 128 + mi * 16 + lg * 4;
#pragma unroll
    for (int ni = 0; ni < 4; ++ni) {
      const int n = n0 + wn * 64 + ni * 16 + lr;
      const float bv = bias[n];
      if (EPI == 1) {
#pragma unroll
        for (int r = 0; r < 4; ++r)
          outf[(size_t)(mbase + r) * N + n] = acc[mi][ni][r] + bv;
      } else {
        const int which = n >> 11;           // 0=q 1=k 2=v
        const int cc = n & 2047, h = cc >> 7, dd = cc & 127;
        const int b = mbase >> 11, t0 = mbase & 2047;  // 4-row group never
        const int bh = b * 16 + h;                     // crosses b boundary
        if (which == 2) {
          bf16x4 pk;
#pragma unroll
          for (int r = 0; r < 4; ++r) pk[r] = (bf16)(acc[mi][ni][r] + bv);
          *(bf16x4*)&vtb[((size_t)bh * 128 + dd) * 2048 + t0] = pk;
        } else {
          bf16* dst = (which == 0) ? qb : kb;
#pragma unroll
          for (int r = 0; r < 4; ++r)
            dst[((size_t)bh * 2048 + t0 + r) * 128 + dd] =
                (bf16)(acc[mi][ni][r] + bv);
        }
      }
    }
  }
}

// ---------------------------------------------------------------------------
// Flash attention, causal, WORK-BALANCED pairing. grid = (8, B*H), 512 thr.
// Block x owns q-tiles qtA = x (waves 0-3) and qtB = 15-x (waves 4-7):
// every block does exactly 34 group-steps of compute. All 8 waves co-stage
// the shared K/V tiles (B's kt range contains A's). Per wave: 2 q-groups of
// 16 rows. K/V LDS dbuf + counted vmcnt + XOR swizzle. (unchanged)
__global__ __launch_bounds__(512) void attn_kernel(
    const bf16* __restrict__ qb, const bf16* __restrict__ kb,
    const bf16* __restrict__ vtb, bf16* __restrict__ ob) {
  __shared__ bf16 Ks[2][64 * 128];  // 2 x 16 KB, swizzled
  __shared__ bf16 Vs[2][128 * 64];  // 2 x 16 KB, swizzled
  __shared__ bf16 Ps[8][16][72];    // per-wave P, pad 64->72 (18 KB)
  const int tid = threadIdx.x, lane = tid & 63, w = tid >> 6;
  const int bh = blockIdx.y;
  const int qtA = blockIdx.x;            // 0..7
  const int qtB = 15 - qtA;              // 8..15
  const int qt_w = (w < 4) ? qtA : qtB;  // this wave's q-tile
  const int wq = w & 3;                  // wave slot within its q-tile
  const int lr = lane & 15, lg = lane >> 4;
  const int q0 = qt_w * 128;
  const size_t base = (size_t)bh * (2048 * 128);
  const int rswz = (lr & 7) << 3;  // read-side XOR (element domain)

  // hoist Q frags; fold (1/sqrt(D))*log2(e) so softmax runs in exp2 domain
  const float qscale = 0.08838834764831845f * 1.4426950408889634f;
  bf16x8 qf[2][4];
#pragma unroll
  for (int g = 0; g < 2; ++g) {
    const bf16* qp =
        qb + base + (size_t)(q0 + g * 64 + wq * 16 + lr) * 128 + lg * 8;
#pragma unroll
    for (int kk = 0; kk < 4; ++kk) {
      bf16x8 t = *(const bf16x8*)(qp + kk * 32);
#pragma unroll
      for (int e = 0; e < 8; ++e) t[e] = (bf16)((float)t[e] * qscale);
      qf[g][kk] = t;
    }
  }

  f32x4 o[2][8] = {};
  float mst[2][4], lst[2][4];
#pragma unroll
  for (int g = 0; g < 2; ++g)
#pragma unroll
    for (int r = 0; r < 4; ++r) { mst[g][r] = -1e30f; lst[g][r] = 0.f; }

  // stage tile kt into buffer bsel: 512 threads x 2 sweeps x (K+V) -> 4
  // gload_lds per thread. dest linear per wave; source col pre-XOR'd.
  auto STAGE = [&](int bsel, int kt) {
#pragma unroll
    for (int c = 0; c < 2; ++c) {
      const int L = w * 1024 + c * 8192 + lane * 16;  // byte offset in 16KB
      {  // K tile rows 256B
        const int row = L >> 8, ce = (L & 255) >> 1;
        gload_lds16(kb + base + (size_t)(kt * 64 + row) * 128 +
                        (ce ^ ((row & 7) << 3)),
                    (char*)Ks[bsel] + w * 1024 + c * 8192);
      }
      {  // V^T tile rows 128B
        const int d = L >> 7, ce = (L & 127) >> 1;
        gload_lds16(vtb + base + (size_t)d * 2048 + kt * 64 +
                        (ce ^ ((d & 7) << 3)),
                    (char*)Vs[bsel] + w * 1024 + c * 8192);
      }
    }
  };

  const int nst = 2 * qtB + 2;  // staged tiles (covers A's range too)
  STAGE(0, 0);                  // 4 outstanding; drained by iter 0's vmcnt(4)
  for (int kt = 0; kt < nst; ++kt) {
    const int cur = kt & 1;
    if (kt + 1 < nst) {
      STAGE(cur ^ 1, kt + 1);  // 4 more in flight
      asm volatile("s_waitcnt vmcnt(4)" ::: "memory");  // tile kt landed
    } else {
      asm volatile("s_waitcnt vmcnt(0)" ::: "memory");
    }
    __builtin_amdgcn_s_barrier();  // all waves' staging of kt visible
    __builtin_amdgcn_sched_barrier(0);

    const bf16* Kc = Ks[cur];
    const bf16* Vc = Vs[cur];
#pragma unroll
    for (int g = 0; g < 2; ++g) {
      if (kt > 2 * qt_w + g) continue;  // wave-uniform: past this group's diag
      const bool diag = (kt == 2 * qt_w + g);

      // S = Q K^T : B-frag col=lr -> K row j*16+lr (swizzled read)
      f32x4 s[4] = {};
      __builtin_amdgcn_s_setprio(1);
#pragma unroll
      for (int kk = 0; kk < 4; ++kk)
#pragma unroll
        for (int j = 0; j < 4; ++j) {
          const bf16x8 kf = *(const bf16x8*)&Kc[(j * 16 + lr) * 128 +
                                               ((kk * 32 + lg * 8) ^ rswz)];
          s[j] = __builtin_amdgcn_mfma_f32_16x16x32_bf16(qf[g][kk], kf, s[j],
                                                         0, 0, 0);
        }
      __builtin_amdgcn_s_setprio(0);

      if (diag) {
#pragma unroll
        for (int j = 0; j < 4; ++j)
#pragma unroll
          for (int r = 0; r < 4; ++r) {
            const int qq = wq * 16 + lg * 4 + r;  // q rel in 64-row group
            if (j * 16 + lr > qq) s[j][r] = -1e30f;
          }
      }

      // online softmax (exp2 domain); q-row = 16 lanes of one lg-group
      float pmax[4];
#pragma unroll
      for (int r = 0; r < 4; ++r) {
        float pm = fmaxf(fmaxf(s[0][r], s[1][r]), fmaxf(s[2][r], s[3][r]));
        pm = fmaxf(pm, __shfl_xor(pm, 1, 16));
        pm = fmaxf(pm, __shfl_xor(pm, 2, 16));
        pm = fmaxf(pm, __shfl_xor(pm, 4, 16));
        pm = fmaxf(pm, __shfl_xor(pm, 8, 16));
        pmax[r] = pm;
      }
      bool need = false;
#pragma unroll
      for (int r = 0; r < 4; ++r) need |= (pmax[r] > mst[g][r]);
      if (__any(need)) {  // skip rescale pass when no row's max grew (exact)
#pragma unroll
        for (int r = 0; r < 4; ++r) {
          const float mnew = fmaxf(mst[g][r], pmax[r]);
          const float alpha = __builtin_amdgcn_exp2f(mst[g][r] - mnew);
          mst[g][r] = mnew;
          lst[g][r] *= alpha;
#pragma unroll
          for (int n = 0; n < 8; ++n) o[g][n][r] *= alpha;
        }
      }
      float rsum[4] = {0.f, 0.f, 0.f, 0.f};
#pragma unroll
      for (int j = 0; j < 4; ++j)
#pragma unroll
        for (int r = 0; r < 4; ++r) {
          const float p = __builtin_amdgcn_exp2f(s[j][r] - mst[g][r]);
          rsum[r] += p;
          Ps[w][lg * 4 + r][j * 16 + lr] = (bf16)p;
        }
#pragma unroll
      for (int r = 0; r < 4; ++r) {
        rsum[r] += __shfl_xor(rsum[r], 1, 16);
        rsum[r] += __shfl_xor(rsum[r], 2, 16);
        rsum[r] += __shfl_xor(rsum[r], 4, 16);
        rsum[r] += __shfl_xor(rsum[r], 8, 16);
        lst[g][r] += rsum[r];
      }

      // P (via per-wave LDS, within-wave ordering) @ V (swizzled read)
      bf16x8 pf[2];
#pragma unroll
      for (int kk = 0; kk < 2; ++kk)
        pf[kk] = *(const bf16x8*)&Ps[w][lr][kk * 32 + lg * 8];
      __builtin_amdgcn_s_setprio(1);
#pragma unroll
      for (int n = 0; n < 8; ++n)
#pragma unroll
        for (int kk = 0; kk < 2; ++kk) {
          const bf16x8 vf = *(const bf16x8*)&Vc[(n * 16 + lr) * 64 +
                                               ((kk * 32 + lg * 8) ^ rswz)];
          o[g][n] = __builtin_amdgcn_mfma_f32_16x16x32_bf16(pf[kk], vf,
                                                            o[g][n], 0, 0, 0);
        }
      __builtin_amdgcn_s_setprio(0);
    }
    __builtin_amdgcn_sched_barrier(0);
    __builtin_amdgcn_s_barrier();  // all reads of buf cur done before next
    __builtin_amdgcn_sched_barrier(0);  // STAGE overwrites it
  }

  // write attn-out as bf16 [B*T][C]
  const int b = bh >> 4, h = bh & 15;
#pragma unroll
  for (int g = 0; g < 2; ++g)
#pragma unroll
    for (int r = 0; r < 4; ++r) {
      const float inv = 1.0f / lst[g][r];
      const int t = q0 + g * 64 + wq * 16 + lg * 4 + r;
      bf16* dst = ob + ((size_t)(b * 2048 + t)) * 2048 + h * 128;
#pragma unroll
      for (int n = 0; n < 8; ++n) dst[n * 16 + lr] = (bf16)(o[g][n][r] * inv);
    }
}

// ---------------------------------------------------------------------------
extern "C" void kernel_launch(void* const* d_in, const int* in_sizes, int n_in,
                              void* d_out, int out_size, void* d_ws,
                              size_t ws_size, hipStream_t stream) {
  const float* x = (const float*)d_in[0];      // [4,2048,2048]
  const float* Wqkv = (const float*)d_in[1];   // [2048,6144]
  const float* bqkv = (const float*)d_in[2];   // [6144]
  const float* Wproj = (const float*)d_in[3];  // [2048,2048]
  const float* bproj = (const float*)d_in[4];  // [2048]
  float* out = (float*)d_out;                  // [8192,2048] fp32

  char* ws = (char*)d_ws;  // needs ~192 MiB
  bf16* xb     = (bf16*)(ws);                  // 33554432 B  x bf16
  bf16* wqkvT  = (bf16*)(ws + 33554432);       // 25165824 B  Wqkv^T
  bf16* wprojT = (bf16*)(ws + 58720256);       //  8388608 B  Wproj^T
  bf16* qb     = (bf16*)(ws + 67108864);       // 33554432 B  Q [BH][T][D]
  bf16* kb     = (bf16*)(ws + 100663296);      // 33554432 B  K [BH][T][D]
  bf16* vtb    = (bf16*)(ws + 134217728);      // 33554432 B  V^T [BH][D][T]
  bf16* ab     = (bf16*)(ws + 167772160);      // 33554432 B  attn out bf16

  cast_f32_bf16<<<8192, 256, 0, stream>>>(x, xb, 2097152);
  transpose_cast<<<dim3(192, 64), 256, 0, stream>>>(Wqkv, wqkvT, 2048, 6144);
  transpose_cast<<<dim3(64, 64), 256, 0, stream>>>(Wproj, wprojT, 2048, 2048);
  gemm256<0><<<768, 512, 0, stream>>>(xb, wqkvT, bqkv, 8192, 6144, 2048,
                                      nullptr, qb, kb, vtb);
  attn_kernel<<<dim3(8, 64), 512, 0, stream>>>(qb, kb, vtb, ab);
  gemm256<1><<<256, 512, 0, stream>>>(ab, wprojT, bproj, 8192, 2048, 2048,
                                      out, nullptr, nullptr, nullptr);
}

// Round 12
// 659.054 us; speedup vs baseline: 3.7215x; 3.7215x over previous
//
#include <hip/hip_runtime.h>

// ---------------------------------------------------------------------------
// Fused MHA: qkv = x@Wqkv+b ; causal attention ; out = attn@Wproj+b
// B=4, T=2048, C=2048, H=16, D=128. fp32 in/out, bf16 MFMA internally.
// ---------------------------------------------------------------------------

typedef __bf16 bf16;
typedef __bf16 bf16x8 __attribute__((ext_vector_type(8)));
typedef __bf16 bf16x4 __attribute__((ext_vector_type(4)));
typedef float f32x4 __attribute__((ext_vector_type(4)));

__device__ __forceinline__ void gload_lds16(const void* g, void* l) {
  __builtin_amdgcn_global_load_lds(
      (const __attribute__((address_space(1))) void*)g,
      (__attribute__((address_space(3))) void*)l, 16, 0, 0);
}

// ---------------------------------------------------------------------------
// cast fp32 -> bf16, 8 elems/thread
__global__ __launch_bounds__(256) void cast_f32_bf16(
    const float* __restrict__ in, bf16* __restrict__ out, int n8) {
  int i = blockIdx.x * 256 + threadIdx.x;
  if (i >= n8) return;
  const float4* p = (const float4*)in + (size_t)i * 2;
  float4 a = p[0], b = p[1];
  bf16x8 o8 = {(bf16)a.x, (bf16)a.y, (bf16)a.z, (bf16)a.w,
               (bf16)b.x, (bf16)b.y, (bf16)b.z, (bf16)b.w};
  *(bf16x8*)(out + (size_t)i * 8) = o8;
}

// ---------------------------------------------------------------------------
// W [R][C] fp32  ->  WT [C][R] bf16   (32x32 LDS tile transpose)
__global__ __launch_bounds__(256) void transpose_cast(
    const float* __restrict__ in, bf16* __restrict__ out, int R, int C) {
  __shared__ bf16 tile[32][33];
  const int r0 = blockIdx.y * 32, c0 = blockIdx.x * 32;
  const int tid = threadIdx.x;
  const int c = tid & 31, r = tid >> 5;
#pragma unroll
  for (int rr = r; rr < 32; rr += 8)
    tile[rr][c] = (bf16)in[(size_t)(r0 + rr) * C + c0 + c];
  __syncthreads();
  const int oc = tid >> 3;           // out row within tile (0..31)
  const int ok = (tid & 7) * 4;      // out col chunk
  bf16x4 v;
#pragma unroll
  for (int j = 0; j < 4; ++j) v[j] = tile[ok + j][oc];
  *(bf16x4*)&out[(size_t)(c0 + oc) * R + r0 + ok] = v;
}

// ---------------------------------------------------------------------------
// 128x128 GEMM, m97 structure (3 blocks/CU): C = A @ BT^T + bias.
// Rationale (R11 post-mortem): R2/R3's 128x128 m97-structure delivered
// g0+g1 ~308us; every 256x256 single-block schedule (R4-R9) was >=357us.
// The 128 tile's ~160 VGPR -> 3 waves/SIMD -> 3 co-resident blocks/CU whose
// independent barriers give free MFMA/mem co-scheduling (m114/m98: 37%+43%).
// Upgrades over R1: both-sides XOR swizzle (bank-conflict 0, proven R4-R9)
// + bijective XCD swizzle. No setprio (m190: null in lockstep GEMM).
// A [M][K] bf16 row-major, BT [N][K] bf16. 256 thr = 4 waves (2M x 2N),
// per-wave 64x64 = acc[4][4]. BK=32; LDS [128][32] per op = 16 KB total.
// Per K-step: s_barrier (prev readers done) -> STAGE (4 gload_lds/thread,
// source col pre-XOR'd by row-bit3) -> vmcnt(0) -> s_barrier -> COMPUTE
// (8 swizzled ds_read_b128 + 16 MFMA, compiler-scheduled).
// EPI 0: scatter Q [BH][T][D], K [BH][T][D], V^T [BH][D][T]; EPI 1: fp32+bias.
template <int EPI>
__global__ __launch_bounds__(256) void gemm128(
    const bf16* __restrict__ A, const bf16* __restrict__ BT,
    const float* __restrict__ bias, int M, int N, int K,
    float* __restrict__ outf, bf16* __restrict__ qb, bf16* __restrict__ kb,
    bf16* __restrict__ vtb) {
  __shared__ bf16 As[128 * 32];  // 8 KB
  __shared__ bf16 Bs[128 * 32];  // 8 KB
  const int tid = threadIdx.x;
  const int lane = tid & 63, w = tid >> 6;
  const int wm = w >> 1, wn = w & 1;
  const int lr = lane & 15, lg = lane >> 4;

  // bijective XCD swizzle (gridDim.x % 8 == 0 for both instantiations)
  const int nwg = gridDim.x, cpx = nwg >> 3;
  const int swz = (blockIdx.x & 7) * cpx + (blockIdx.x >> 3);
  const int ntx = N >> 7;  // tiles along N
  const int m0 = (swz / ntx) * 128, n0 = (swz % ntx) * 128;

  // stage K-step k0: A 8KB + B 8KB; 2 sweeps x 2 ops = 4 gload_lds/thread.
  // dest linear; source col pre-XOR'd by row-bit3 (both-sides swizzle:
  // rows are 64B so LDS byte bit9 = row bit3; swizzled bit = byte bit5).
  auto STAGE = [&](int k0) {
#pragma unroll
    for (int s = 0; s < 2; ++s) {
      const bf16* src = s ? BT : A;
      const int r0 = s ? n0 : m0;
      bf16* lb = s ? Bs : As;
#pragma unroll
      for (int c = 0; c < 2; ++c) {
        const int off = tid * 16 + c * 4096;       // byte offset in 8KB
        const int row = off >> 6;                  // 0..127
        const int ce = ((off & 63) >> 1) ^ ((row & 8) ? 16 : 0);
        gload_lds16(src + (size_t)(r0 + row) * K + k0 + ce,
                    (char*)lb + (w * 1024 + c * 4096) + (lane * 16));
      }
    }
  };
  // fragment reads (swizzled): logical (row, lg*8..+7); row bit3 = lr bit3
  auto LDA = [&](int mi) -> bf16x8 {
    const int row = wm * 64 + mi * 16 + lr;
    return *(const bf16x8*)((const char*)As +
                            ((row * 64 + lg * 16) ^ ((lr >> 3) << 5)));
  };
  auto LDB = [&](int ni) -> bf16x8 {
    const int row = wn * 64 + ni * 16 + lr;
    return *(const bf16x8*)((const char*)Bs +
                            ((row * 64 + lg * 16) ^ ((lr >> 3) << 5)));
  };

  f32x4 acc[4][4] = {};

  for (int k0 = 0; k0 < K; k0 += 32) {
    __builtin_amdgcn_s_barrier();  // prev iteration's readers done
    STAGE(k0);
    asm volatile("s_waitcnt vmcnt(0)" ::: "memory");
    __builtin_amdgcn_s_barrier();  // tile visible to all waves
    bf16x8 af[4], bfr[4];
#pragma unroll
    for (int i = 0; i < 4; ++i) {
      af[i] = LDA(i);
      bfr[i] = LDB(i);
    }
#pragma unroll
    for (int mi = 0; mi < 4; ++mi)
#pragma unroll
      for (int ni = 0; ni < 4; ++ni)
        acc[mi][ni] = __builtin_amdgcn_mfma_f32_16x16x32_bf16(
            af[mi], bfr[ni], acc[mi][ni], 0, 0, 0);
  }

  // epilogue: C/D layout col=lane&15, row=(lane>>4)*4+r  [m89/m91]
#pragma unroll
  for (int mi = 0; mi < 4; ++mi) {
    const int mbase = m0 + wm * 64 + mi * 16 + lg * 4;
#pragma unroll
    for (int ni = 0; ni < 4; ++ni) {
      const int n = n0 + wn * 64 + ni * 16 + lr;
      const float bv = bias[n];
      if (EPI == 1) {
#pragma unroll
        for (int r = 0; r < 4; ++r)
          outf[(size_t)(mbase + r) * N + n] = acc[mi][ni][r] + bv;
      } else {
        const int which = n >> 11;           // 0=q 1=k 2=v
        const int cc = n & 2047, h = cc >> 7, dd = cc & 127;
        const int b = mbase >> 11, t0 = mbase & 2047;  // 4-row group never
        const int bh = b * 16 + h;                     // crosses b boundary
        if (which == 2) {
          bf16x4 pk;
#pragma unroll
          for (int r = 0; r < 4; ++r) pk[r] = (bf16)(acc[mi][ni][r] + bv);
          *(bf16x4*)&vtb[((size_t)bh * 128 + dd) * 2048 + t0] = pk;
        } else {
          bf16* dst = (which == 0) ? qb : kb;
#pragma unroll
          for (int r = 0; r < 4; ++r)
            dst[((size_t)bh * 2048 + t0 + r) * 128 + dd] =
                (bf16)(acc[mi][ni][r] + bv);
        }
      }
    }
  }
}

// ---------------------------------------------------------------------------
// Flash attention, causal, WORK-BALANCED pairing. grid = (8, B*H), 512 thr.
// Block x owns q-tiles qtA = x (waves 0-3) and qtB = 15-x (waves 4-7):
// every block does exactly 34 group-steps of compute. All 8 waves co-stage
// the shared K/V tiles (B's kt range contains A's). Per wave: 2 q-groups of
// 16 rows. K/V LDS dbuf + counted vmcnt + XOR swizzle. (R7 version, unchanged)
__global__ __launch_bounds__(512) void attn_kernel(
    const bf16* __restrict__ qb, const bf16* __restrict__ kb,
    const bf16* __restrict__ vtb, bf16* __restrict__ ob) {
  __shared__ bf16 Ks[2][64 * 128];  // 2 x 16 KB, swizzled
  __shared__ bf16 Vs[2][128 * 64];  // 2 x 16 KB, swizzled
  __shared__ bf16 Ps[8][16][72];    // per-wave P, pad 64->72 (18 KB)
  const int tid = threadIdx.x, lane = tid & 63, w = tid >> 6;
  const int bh = blockIdx.y;
  const int qtA = blockIdx.x;            // 0..7
  const int qtB = 15 - qtA;              // 8..15
  const int qt_w = (w < 4) ? qtA : qtB;  // this wave's q-tile
  const int wq = w & 3;                  // wave slot within its q-tile
  const int lr = lane & 15, lg = lane >> 4;
  const int q0 = qt_w * 128;
  const size_t base = (size_t)bh * (2048 * 128);
  const int rswz = (lr & 7) << 3;  // read-side XOR (element domain)

  // hoist Q frags; fold (1/sqrt(D))*log2(e) so softmax runs in exp2 domain
  const float qscale = 0.08838834764831845f * 1.4426950408889634f;
  bf16x8 qf[2][4];
#pragma unroll
  for (int g = 0; g < 2; ++g) {
    const bf16* qp =
        qb + base + (size_t)(q0 + g * 64 + wq * 16 + lr) * 128 + lg * 8;
#pragma unroll
    for (int kk = 0; kk < 4; ++kk) {
      bf16x8 t = *(const bf16x8*)(qp + kk * 32);
#pragma unroll
      for (int e = 0; e < 8; ++e) t[e] = (bf16)((float)t[e] * qscale);
      qf[g][kk] = t;
    }
  }

  f32x4 o[2][8] = {};
  float mst[2][4], lst[2][4];
#pragma unroll
  for (int g = 0; g < 2; ++g)
#pragma unroll
    for (int r = 0; r < 4; ++r) { mst[g][r] = -1e30f; lst[g][r] = 0.f; }

  // stage tile kt into buffer bsel: 512 threads x 2 sweeps x (K+V) -> 4
  // gload_lds per thread. dest linear per wave; source col pre-XOR'd.
  auto STAGE = [&](int bsel, int kt) {
#pragma unroll
    for (int c = 0; c < 2; ++c) {
      const int L = w * 1024 + c * 8192 + lane * 16;  // byte offset in 16KB
      {  // K tile rows 256B
        const int row = L >> 8, ce = (L & 255) >> 1;
        gload_lds16(kb + base + (size_t)(kt * 64 + row) * 128 +
                        (ce ^ ((row & 7) << 3)),
                    (char*)Ks[bsel] + w * 1024 + c * 8192);
      }
      {  // V^T tile rows 128B
        const int d = L >> 7, ce = (L & 127) >> 1;
        gload_lds16(vtb + base + (size_t)d * 2048 + kt * 64 +
                        (ce ^ ((d & 7) << 3)),
                    (char*)Vs[bsel] + w * 1024 + c * 8192);
      }
    }
  };

  const int nst = 2 * qtB + 2;  // staged tiles (covers A's range too)
  STAGE(0, 0);                  // 4 outstanding; drained by iter 0's vmcnt(4)
  for (int kt = 0; kt < nst; ++kt) {
    const int cur = kt & 1;
    if (kt + 1 < nst) {
      STAGE(cur ^ 1, kt + 1);  // 4 more in flight
      asm volatile("s_waitcnt vmcnt(4)" ::: "memory");  // tile kt landed
    } else {
      asm volatile("s_waitcnt vmcnt(0)" ::: "memory");
    }
    __builtin_amdgcn_s_barrier();  // all waves' staging of kt visible
    __builtin_amdgcn_sched_barrier(0);

    const bf16* Kc = Ks[cur];
    const bf16* Vc = Vs[cur];
#pragma unroll
    for (int g = 0; g < 2; ++g) {
      if (kt > 2 * qt_w + g) continue;  // wave-uniform: past this group's diag
      const bool diag = (kt == 2 * qt_w + g);

      // S = Q K^T : B-frag col=lr -> K row j*16+lr (swizzled read)
      f32x4 s[4] = {};
      __builtin_amdgcn_s_setprio(1);
#pragma unroll
      for (int kk = 0; kk < 4; ++kk)
#pragma unroll
        for (int j = 0; j < 4; ++j) {
          const bf16x8 kf = *(const bf16x8*)&Kc[(j * 16 + lr) * 128 +
                                               ((kk * 32 + lg * 8) ^ rswz)];
          s[j] = __builtin_amdgcn_mfma_f32_16x16x32_bf16(qf[g][kk], kf, s[j],
                                                         0, 0, 0);
        }
      __builtin_amdgcn_s_setprio(0);

      if (diag) {
#pragma unroll
        for (int j = 0; j < 4; ++j)
#pragma unroll
          for (int r = 0; r < 4; ++r) {
            const int qq = wq * 16 + lg * 4 + r;  // q rel in 64-row group
            if (j * 16 + lr > qq) s[j][r] = -1e30f;
          }
      }

      // online softmax (exp2 domain); q-row = 16 lanes of one lg-group
      float pmax[4];
#pragma unroll
      for (int r = 0; r < 4; ++r) {
        float pm = fmaxf(fmaxf(s[0][r], s[1][r]), fmaxf(s[2][r], s[3][r]));
        pm = fmaxf(pm, __shfl_xor(pm, 1, 16));
        pm = fmaxf(pm, __shfl_xor(pm, 2, 16));
        pm = fmaxf(pm, __shfl_xor(pm, 4, 16));
        pm = fmaxf(pm, __shfl_xor(pm, 8, 16));
        pmax[r] = pm;
      }
      bool need = false;
#pragma unroll
      for (int r = 0; r < 4; ++r) need |= (pmax[r] > mst[g][r]);
      if (__any(need)) {  // skip rescale pass when no row's max grew (exact)
#pragma unroll
        for (int r = 0; r < 4; ++r) {
          const float mnew = fmaxf(mst[g][r], pmax[r]);
          const float alpha = __builtin_amdgcn_exp2f(mst[g][r] - mnew);
          mst[g][r] = mnew;
          lst[g][r] *= alpha;
#pragma unroll
          for (int n = 0; n < 8; ++n) o[g][n][r] *= alpha;
        }
      }
      float rsum[4] = {0.f, 0.f, 0.f, 0.f};
#pragma unroll
      for (int j = 0; j < 4; ++j)
#pragma unroll
        for (int r = 0; r < 4; ++r) {
          const float p = __builtin_amdgcn_exp2f(s[j][r] - mst[g][r]);
          rsum[r] += p;
          Ps[w][lg * 4 + r][j * 16 + lr] = (bf16)p;
        }
#pragma unroll
      for (int r = 0; r < 4; ++r) {
        rsum[r] += __shfl_xor(rsum[r], 1, 16);
        rsum[r] += __shfl_xor(rsum[r], 2, 16);
        rsum[r] += __shfl_xor(rsum[r], 4, 16);
        rsum[r] += __shfl_xor(rsum[r], 8, 16);
        lst[g][r] += rsum[r];
      }

      // P (via per-wave LDS, within-wave ordering) @ V (swizzled read)
      bf16x8 pf[2];
#pragma unroll
      for (int kk = 0; kk < 2; ++kk)
        pf[kk] = *(const bf16x8*)&Ps[w][lr][kk * 32 + lg * 8];
      __builtin_amdgcn_s_setprio(1);
#pragma unroll
      for (int n = 0; n < 8; ++n)
#pragma unroll
        for (int kk = 0; kk < 2; ++kk) {
          const bf16x8 vf = *(const bf16x8*)&Vc[(n * 16 + lr) * 64 +
                                               ((kk * 32 + lg * 8) ^ rswz)];
          o[g][n] = __builtin_amdgcn_mfma_f32_16x16x32_bf16(pf[kk], vf,
                                                            o[g][n], 0, 0, 0);
        }
      __builtin_amdgcn_s_setprio(0);
    }
    __builtin_amdgcn_sched_barrier(0);
    __builtin_amdgcn_s_barrier();  // all reads of buf cur done before next
    __builtin_amdgcn_sched_barrier(0);  // STAGE overwrites it
  }

  // write attn-out as bf16 [B*T][C]
  const int b = bh >> 4, h = bh & 15;
#pragma unroll
  for (int g = 0; g < 2; ++g)
#pragma unroll
    for (int r = 0; r < 4; ++r) {
      const float inv = 1.0f / lst[g][r];
      const int t = q0 + g * 64 + wq * 16 + lg * 4 + r;
      bf16* dst = ob + ((size_t)(b * 2048 + t)) * 2048 + h * 128;
#pragma unroll
      for (int n = 0; n < 8; ++n) dst[n * 16 + lr] = (bf16)(o[g][n][r] * inv);
    }
}

// ---------------------------------------------------------------------------
extern "C" void kernel_launch(void* const* d_in, const int* in_sizes, int n_in,
                              void* d_out, int out_size, void* d_ws,
                              size_t ws_size, hipStream_t stream) {
  const float* x = (const float*)d_in[0];      // [4,2048,2048]
  const float* Wqkv = (const float*)d_in[1];   // [2048,6144]
  const float* bqkv = (const float*)d_in[2];   // [6144]
  const float* Wproj = (const float*)d_in[3];  // [2048,2048]
  const float* bproj = (const float*)d_in[4];  // [2048]
  float* out = (float*)d_out;                  // [8192,2048] fp32

  char* ws = (char*)d_ws;  // needs ~192 MiB
  bf16* xb     = (bf16*)(ws);                  // 33554432 B  x bf16
  bf16* wqkvT  = (bf16*)(ws + 33554432);       // 25165824 B  Wqkv^T
  bf16* wprojT = (bf16*)(ws + 58720256);       //  8388608 B  Wproj^T
  bf16* qb     = (bf16*)(ws + 67108864);       // 33554432 B  Q [BH][T][D]
  bf16* kb     = (bf16*)(ws + 100663296);      // 33554432 B  K [BH][T][D]
  bf16* vtb    = (bf16*)(ws + 134217728);      // 33554432 B  V^T [BH][D][T]
  bf16* ab     = (bf16*)(ws + 167772160);      // 33554432 B  attn out bf16

  cast_f32_bf16<<<8192, 256, 0, stream>>>(x, xb, 2097152);
  transpose_cast<<<dim3(192, 64), 256, 0, stream>>>(Wqkv, wqkvT, 2048, 6144);
  transpose_cast<<<dim3(64, 64), 256, 0, stream>>>(Wproj, wprojT, 2048, 2048);
  gemm128<0><<<3072, 256, 0, stream>>>(xb, wqkvT, bqkv, 8192, 6144, 2048,
                                       nullptr, qb, kb, vtb);
  attn_kernel<<<dim3(8, 64), 512, 0, stream>>>(qb, kb, vtb, ab);
  gemm128<1><<<1024, 256, 0, stream>>>(ab, wprojT, bproj, 8192, 2048, 2048,
                                       out, nullptr, nullptr, nullptr);
}

// Round 13
// 599.009 us; speedup vs baseline: 4.0946x; 1.1002x over previous
//
#include <hip/hip_runtime.h>

// ---------------------------------------------------------------------------
// Fused MHA: qkv = x@Wqkv+b ; causal attention ; out = attn@Wproj+b
// B=4, T=2048, C=2048, H=16, D=128. fp32 in/out, bf16 MFMA internally.
// GEMM = R8 best-measured 256x256 (267us g0). attn = R7 + 80KB LDS
// (2 blocks/CU) + defer-max THR.
// ---------------------------------------------------------------------------

typedef __bf16 bf16;
typedef __bf16 bf16x8 __attribute__((ext_vector_type(8)));
typedef __bf16 bf16x4 __attribute__((ext_vector_type(4)));
typedef float f32x4 __attribute__((ext_vector_type(4)));

__device__ __forceinline__ void gload_lds16(const void* g, void* l) {
  __builtin_amdgcn_global_load_lds(
      (const __attribute__((address_space(1))) void*)g,
      (__attribute__((address_space(3))) void*)l, 16, 0, 0);
}

// ---------------------------------------------------------------------------
// cast fp32 -> bf16, 8 elems/thread
__global__ __launch_bounds__(256) void cast_f32_bf16(
    const float* __restrict__ in, bf16* __restrict__ out, int n8) {
  int i = blockIdx.x * 256 + threadIdx.x;
  if (i >= n8) return;
  const float4* p = (const float4*)in + (size_t)i * 2;
  float4 a = p[0], b = p[1];
  bf16x8 o8 = {(bf16)a.x, (bf16)a.y, (bf16)a.z, (bf16)a.w,
               (bf16)b.x, (bf16)b.y, (bf16)b.z, (bf16)b.w};
  *(bf16x8*)(out + (size_t)i * 8) = o8;
}

// ---------------------------------------------------------------------------
// W [R][C] fp32  ->  WT [C][R] bf16   (32x32 LDS tile transpose)
__global__ __launch_bounds__(256) void transpose_cast(
    const float* __restrict__ in, bf16* __restrict__ out, int R, int C) {
  __shared__ bf16 tile[32][33];
  const int r0 = blockIdx.y * 32, c0 = blockIdx.x * 32;
  const int tid = threadIdx.x;
  const int c = tid & 31, r = tid >> 5;
#pragma unroll
  for (int rr = r; rr < 32; rr += 8)
    tile[rr][c] = (bf16)in[(size_t)(r0 + rr) * C + c0 + c];
  __syncthreads();
  const int oc = tid >> 3;           // out row within tile (0..31)
  const int ok = (tid & 7) * 4;      // out col chunk
  bf16x4 v;
#pragma unroll
  for (int j = 0; j < 4; ++j) v[j] = tile[ok + j][oc];
  *(bf16x4*)&out[(size_t)(c0 + oc) * R + r0 + ok] = v;
}

// ---------------------------------------------------------------------------
// 256x256 GEMM (R8 best-measured version, verbatim): C = A @ BT^T + bias.
// 512 thr = 8 waves (2M x 4N), BK=64 as 2 K-halves of 32. LDS 128 KiB dbuf,
// 64B rows, swizzle byte-bit5 ^= row-bit3 both-sides. Per K-tile: issue all
// 8 stage loads for t+1 -> setprio(1) -> COMPUTE kh0+kh1 (24 ds_read + 64
// MFMA, one compiler-scheduled scope) -> setprio(0) -> vmcnt(0) -> barrier.
template <int EPI>
__global__ __launch_bounds__(512, 2) void gemm256(
    const bf16* __restrict__ A, const bf16* __restrict__ BT,
    const float* __restrict__ bias, int M, int N, int K,
    float* __restrict__ outf, bf16* __restrict__ qb, bf16* __restrict__ kb,
    bf16* __restrict__ vtb) {
  __shared__ bf16 As[2][2][256 * 32];  // 64 KB
  __shared__ bf16 Bs[2][2][256 * 32];  // 64 KB
  const int tid = threadIdx.x;
  const int lane = tid & 63, w = tid >> 6;
  const int wm = w >> 2, wn = w & 3;
  const int lr = lane & 15, lg = lane >> 4;

  // bijective XCD swizzle (gridDim.x % 8 == 0 for both instantiations)
  const int nwg = gridDim.x, cpx = nwg >> 3;
  const int swz = (blockIdx.x & 7) * cpx + (blockIdx.x >> 3);
  const int ntx = N >> 8;  // tiles along N
  const int m0 = (swz / ntx) * 256, n0 = (swz % ntx) * 256;

  // stage one 16KB half-tile (kh, operand) of K-tile kt into dbuf d.
  // dest linear; source col pre-XOR'd by row-bit3 (both-sides swizzle).
  auto STAGE_H = [&](int d, int skh, int sisB, int kt) {
    const bf16* src = sisB ? BT : A;
    const int r0 = sisB ? n0 : m0;
    bf16* lb = sisB ? &Bs[d][skh][0] : &As[d][skh][0];
#pragma unroll
    for (int c = 0; c < 2; ++c) {
      const int chunk = w * 2 + c;                    // 0..15 (1KB chunks)
      const int row = chunk * 16 + (lane >> 2);       // 0..255
      const int col = ((lane & 3) * 8) ^ (((row >> 3) & 1) << 4);
      gload_lds16(src + (size_t)(r0 + row) * K + kt * 64 + skh * 32 + col,
                  (char*)lb + chunk * 1024);
    }
  };
  // fragment reads (swizzled): logical (row, lg*8..+7) of K-half kh
  auto LDA = [&](int d, int kh, int mi) -> bf16x8 {
    const int row = wm * 128 + mi * 16 + lr;
    return *(const bf16x8*)((const char*)&As[d][kh][0] +
                            ((row * 64 + lg * 16) ^ ((lr >> 3) << 5)));
  };
  auto LDB = [&](int d, int kh, int ni) -> bf16x8 {
    const int row = wn * 64 + ni * 16 + lr;
    return *(const bf16x8*)((const char*)&Bs[d][kh][0] +
                            ((row * 64 + lg * 16) ^ ((lr >> 3) << 5)));
  };

  f32x4 acc[8][4] = {};
  const int NT = K >> 6;

  // one half-K compute: 12 ds_read + 32 MFMA, compiler-scheduled
  auto COMPUTE = [&](int d, int kh) {
    bf16x8 af[8], bfr[4];
#pragma unroll
    for (int mi = 0; mi < 8; ++mi) af[mi] = LDA(d, kh, mi);
#pragma unroll
    for (int ni = 0; ni < 4; ++ni) bfr[ni] = LDB(d, kh, ni);
#pragma unroll
    for (int mi = 0; mi < 8; ++mi)
#pragma unroll
      for (int ni = 0; ni < 4; ++ni)
        acc[mi][ni] = __builtin_amdgcn_mfma_f32_16x16x32_bf16(
            af[mi], bfr[ni], acc[mi][ni], 0, 0, 0);
  };

  // prologue: stage tile 0 fully, drain, sync
  STAGE_H(0, 0, 0, 0);
  STAGE_H(0, 0, 1, 0);
  STAGE_H(0, 1, 0, 0);
  STAGE_H(0, 1, 1, 0);
  asm volatile("s_waitcnt vmcnt(0)" ::: "memory");
  __builtin_amdgcn_s_barrier();

  for (int t = 0; t < NT; ++t) {
    const int cur = t & 1;
    if (t + 1 < NT) {  // issue next tile's 8 loads; they fly under 64 MFMA
      STAGE_H(cur ^ 1, 0, 0, t + 1);
      STAGE_H(cur ^ 1, 0, 1, t + 1);
      STAGE_H(cur ^ 1, 1, 0, t + 1);
      STAGE_H(cur ^ 1, 1, 1, t + 1);
    }
    __builtin_amdgcn_s_setprio(1);
    COMPUTE(cur, 0);
    COMPUTE(cur, 1);
    __builtin_amdgcn_s_setprio(0);
    asm volatile("s_waitcnt vmcnt(0)" ::: "memory");
    __builtin_amdgcn_s_barrier();  // buf cur free + t+1 data visible
  }

  // epilogue: C/D layout col=lane&15, row=(lane>>4)*4+r  [m89/m91]
#pragma unroll
  for (int mi = 0; mi < 8; ++mi) {
    const int mbase = m0 + wm * 128 + mi * 16 + lg * 4;
#pragma unroll
    for (int ni = 0; ni < 4; ++ni) {
      const int n = n0 + wn * 64 + ni * 16 + lr;
      const float bv = bias[n];
      if (EPI == 1) {
#pragma unroll
        for (int r = 0; r < 4; ++r)
          outf[(size_t)(mbase + r) * N + n] = acc[mi][ni][r] + bv;
      } else {
        const int which = n >> 11;           // 0=q 1=k 2=v
        const int cc = n & 2047, h = cc >> 7, dd = cc & 127;
        const int b = mbase >> 11, t0 = mbase & 2047;  // 4-row group never
        const int bh = b * 16 + h;                     // crosses b boundary
        if (which == 2) {
          bf16x4 pk;
#pragma unroll
          for (int r = 0; r < 4; ++r) pk[r] = (bf16)(acc[mi][ni][r] + bv);
          *(bf16x4*)&vtb[((size_t)bh * 128 + dd) * 2048 + t0] = pk;
        } else {
          bf16* dst = (which == 0) ? qb : kb;
#pragma unroll
          for (int r = 0; r < 4; ++r)
            dst[((size_t)bh * 2048 + t0 + r) * 128 + dd] =
                (bf16)(acc[mi][ni][r] + bv);
        }
      }
    }
  }
}

// ---------------------------------------------------------------------------
// Flash attention, causal, WORK-BALANCED pairing (R7 structure), now at
// LDS = 80 KB EXACTLY -> 2 blocks/CU (grid 512 = 2/CU, fully resident,
// independent barriers give cross-block MFMA/mem overlap). Achieved by
// replacing Ps's 72-pad with XOR-swizzle on [16][64] (write col ^
// ((row&7)*8), read same XOR -> 2-way aliasing, free). Also T13 defer-max:
// skip o-rescale unless a row's max grew by >8 (exp2-domain; P <= 2^8).
__global__ __launch_bounds__(512) void attn_kernel(
    const bf16* __restrict__ qb, const bf16* __restrict__ kb,
    const bf16* __restrict__ vtb, bf16* __restrict__ ob) {
  __shared__ bf16 Ks[2][64 * 128];  // 32 KB, swizzled
  __shared__ bf16 Vs[2][128 * 64];  // 32 KB, swizzled
  __shared__ bf16 Ps[8][16 * 64];   // 16 KB, swizzled  -> total 80 KB
  const int tid = threadIdx.x, lane = tid & 63, w = tid >> 6;
  const int bh = blockIdx.y;
  const int qtA = blockIdx.x;            // 0..7
  const int qtB = 15 - qtA;              // 8..15
  const int qt_w = (w < 4) ? qtA : qtB;  // this wave's q-tile
  const int wq = w & 3;                  // wave slot within its q-tile
  const int lr = lane & 15, lg = lane >> 4;
  const int q0 = qt_w * 128;
  const size_t base = (size_t)bh * (2048 * 128);
  const int rswz = (lr & 7) << 3;  // read-side XOR (element domain)

  // hoist Q frags; fold (1/sqrt(D))*log2(e) so softmax runs in exp2 domain
  const float qscale = 0.08838834764831845f * 1.4426950408889634f;
  bf16x8 qf[2][4];
#pragma unroll
  for (int g = 0; g < 2; ++g) {
    const bf16* qp =
        qb + base + (size_t)(q0 + g * 64 + wq * 16 + lr) * 128 + lg * 8;
#pragma unroll
    for (int kk = 0; kk < 4; ++kk) {
      bf16x8 t = *(const bf16x8*)(qp + kk * 32);
#pragma unroll
      for (int e = 0; e < 8; ++e) t[e] = (bf16)((float)t[e] * qscale);
      qf[g][kk] = t;
    }
  }

  f32x4 o[2][8] = {};
  float mst[2][4], lst[2][4];
#pragma unroll
  for (int g = 0; g < 2; ++g)
#pragma unroll
    for (int r = 0; r < 4; ++r) { mst[g][r] = -1e30f; lst[g][r] = 0.f; }

  // stage tile kt into buffer bsel: 512 threads x 2 sweeps x (K+V) -> 4
  // gload_lds per thread. dest linear per wave; source col pre-XOR'd.
  auto STAGE = [&](int bsel, int kt) {
#pragma unroll
    for (int c = 0; c < 2; ++c) {
      const int L = w * 1024 + c * 8192 + lane * 16;  // byte offset in 16KB
      {  // K tile rows 256B
        const int row = L >> 8, ce = (L & 255) >> 1;
        gload_lds16(kb + base + (size_t)(kt * 64 + row) * 128 +
                        (ce ^ ((row & 7) << 3)),
                    (char*)Ks[bsel] + w * 1024 + c * 8192);
      }
      {  // V^T tile rows 128B
        const int d = L >> 7, ce = (L & 127) >> 1;
        gload_lds16(vtb + base + (size_t)d * 2048 + kt * 64 +
                        (ce ^ ((d & 7) << 3)),
                    (char*)Vs[bsel] + w * 1024 + c * 8192);
      }
    }
  };

  const int nst = 2 * qtB + 2;  // staged tiles (covers A's range too)
  STAGE(0, 0);                  // 4 outstanding; drained by iter 0's vmcnt(4)
  for (int kt = 0; kt < nst; ++kt) {
    const int cur = kt & 1;
    if (kt + 1 < nst) {
      STAGE(cur ^ 1, kt + 1);  // 4 more in flight
      asm volatile("s_waitcnt vmcnt(4)" ::: "memory");  // tile kt landed
    } else {
      asm volatile("s_waitcnt vmcnt(0)" ::: "memory");
    }
    __builtin_amdgcn_s_barrier();  // all waves' staging of kt visible
    __builtin_amdgcn_sched_barrier(0);

    const bf16* Kc = Ks[cur];
    const bf16* Vc = Vs[cur];
#pragma unroll
    for (int g = 0; g < 2; ++g) {
      if (kt > 2 * qt_w + g) continue;  // wave-uniform: past this group's diag
      const bool diag = (kt == 2 * qt_w + g);

      // S = Q K^T : B-frag col=lr -> K row j*16+lr (swizzled read)
      f32x4 s[4] = {};
      __builtin_amdgcn_s_setprio(1);
#pragma unroll
      for (int kk = 0; kk < 4; ++kk)
#pragma unroll
        for (int j = 0; j < 4; ++j) {
          const bf16x8 kf = *(const bf16x8*)&Kc[(j * 16 + lr) * 128 +
                                               ((kk * 32 + lg * 8) ^ rswz)];
          s[j] = __builtin_amdgcn_mfma_f32_16x16x32_bf16(qf[g][kk], kf, s[j],
                                                         0, 0, 0);
        }
      __builtin_amdgcn_s_setprio(0);

      if (diag) {
#pragma unroll
        for (int j = 0; j < 4; ++j)
#pragma unroll
          for (int r = 0; r < 4; ++r) {
            const int qq = wq * 16 + lg * 4 + r;  // q rel in 64-row group
            if (j * 16 + lr > qq) s[j][r] = -1e30f;
          }
      }

      // online softmax (exp2 domain); q-row = 16 lanes of one lg-group
      float pmax[4];
#pragma unroll
      for (int r = 0; r < 4; ++r) {
        float pm = fmaxf(fmaxf(s[0][r], s[1][r]), fmaxf(s[2][r], s[3][r]));
        pm = fmaxf(pm, __shfl_xor(pm, 1, 16));
        pm = fmaxf(pm, __shfl_xor(pm, 2, 16));
        pm = fmaxf(pm, __shfl_xor(pm, 4, 16));
        pm = fmaxf(pm, __shfl_xor(pm, 8, 16));
        pmax[r] = pm;
      }
      // T13 defer-max: only rescale when some row's max grew by >8
      // (exp2-domain units; P then bounded by 2^8=256, bf16/f32-safe).
      bool need = false;
#pragma unroll
      for (int r = 0; r < 4; ++r) need |= (pmax[r] > mst[g][r] + 8.0f);
      if (__any(need)) {
#pragma unroll
        for (int r = 0; r < 4; ++r) {
          const float mnew = fmaxf(mst[g][r], pmax[r]);
          const float alpha = __builtin_amdgcn_exp2f(mst[g][r] - mnew);
          mst[g][r] = mnew;
          lst[g][r] *= alpha;
#pragma unroll
          for (int n = 0; n < 8; ++n) o[g][n][r] *= alpha;
        }
      }
      float rsum[4] = {0.f, 0.f, 0.f, 0.f};
#pragma unroll
      for (int j = 0; j < 4; ++j)
#pragma unroll
        for (int r = 0; r < 4; ++r) {
          const float p = __builtin_amdgcn_exp2f(s[j][r] - mst[g][r]);
          rsum[r] += p;
          // Ps write: row=lg*4+r, col=j*16+lr, XOR col by (row&7)*8
          const int prow = lg * 4 + r;
          Ps[w][prow * 64 + ((j * 16 + lr) ^ ((prow & 7) << 3))] = (bf16)p;
        }
#pragma unroll
      for (int r = 0; r < 4; ++r) {
        rsum[r] += __shfl_xor(rsum[r], 1, 16);
        rsum[r] += __shfl_xor(rsum[r], 2, 16);
        rsum[r] += __shfl_xor(rsum[r], 4, 16);
        rsum[r] += __shfl_xor(rsum[r], 8, 16);
        lst[g][r] += rsum[r];
      }

      // P (via per-wave LDS, within-wave ordering) @ V (swizzled reads)
      bf16x8 pf[2];
#pragma unroll
      for (int kk = 0; kk < 2; ++kk)
        pf[kk] = *(const bf16x8*)&Ps[w][lr * 64 +
                                       ((kk * 32 + lg * 8) ^ rswz)];
      __builtin_amdgcn_s_setprio(1);
#pragma unroll
      for (int n = 0; n < 8; ++n)
#pragma unroll
        for (int kk = 0; kk < 2; ++kk) {
          const bf16x8 vf = *(const bf16x8*)&Vc[(n * 16 + lr) * 64 +
                                               ((kk * 32 + lg * 8) ^ rswz)];
          o[g][n] = __builtin_amdgcn_mfma_f32_16x16x32_bf16(pf[kk], vf,
                                                            o[g][n], 0, 0, 0);
        }
      __builtin_amdgcn_s_setprio(0);
    }
    __builtin_amdgcn_sched_barrier(0);
    __builtin_amdgcn_s_barrier();  // all reads of buf cur done before next
    __builtin_amdgcn_sched_barrier(0);  // STAGE overwrites it
  }

  // write attn-out as bf16 [B*T][C]
  const int b = bh >> 4, h = bh & 15;
#pragma unroll
  for (int g = 0; g < 2; ++g)
#pragma unroll
    for (int r = 0; r < 4; ++r) {
      const float inv = 1.0f / lst[g][r];
      const int t = q0 + g * 64 + wq * 16 + lg * 4 + r;
      bf16* dst = ob + ((size_t)(b * 2048 + t)) * 2048 + h * 128;
#pragma unroll
      for (int n = 0; n < 8; ++n) dst[n * 16 + lr] = (bf16)(o[g][n][r] * inv);
    }
}

// ---------------------------------------------------------------------------
extern "C" void kernel_launch(void* const* d_in, const int* in_sizes, int n_in,
                              void* d_out, int out_size, void* d_ws,
                              size_t ws_size, hipStream_t stream) {
  const float* x = (const float*)d_in[0];      // [4,2048,2048]
  const float* Wqkv = (const float*)d_in[1];   // [2048,6144]
  const float* bqkv = (const float*)d_in[2];   // [6144]
  const float* Wproj = (const float*)d_in[3];  // [2048,2048]
  const float* bproj = (const float*)d_in[4];  // [2048]
  float* out = (float*)d_out;                  // [8192,2048] fp32

  char* ws = (char*)d_ws;  // needs ~192 MiB
  bf16* xb     = (bf16*)(ws);                  // 33554432 B  x bf16
  bf16* wqkvT  = (bf16*)(ws + 33554432);       // 25165824 B  Wqkv^T
  bf16* wprojT = (bf16*)(ws + 58720256);       //  8388608 B  Wproj^T
  bf16* qb     = (bf16*)(ws + 67108864);       // 33554432 B  Q [BH][T][D]
  bf16* kb     = (bf16*)(ws + 100663296);      // 33554432 B  K [BH][T][D]
  bf16* vtb    = (bf16*)(ws + 134217728);      // 33554432 B  V^T [BH][D][T]
  bf16* ab     = (bf16*)(ws + 167772160);      // 33554432 B  attn out bf16

  cast_f32_bf16<<<8192, 256, 0, stream>>>(x, xb, 2097152);
  transpose_cast<<<dim3(192, 64), 256, 0, stream>>>(Wqkv, wqkvT, 2048, 6144);
  transpose_cast<<<dim3(64, 64), 256, 0, stream>>>(Wproj, wprojT, 2048, 2048);
  gemm256<0><<<768, 512, 0, stream>>>(xb, wqkvT, bqkv, 8192, 6144, 2048,
                                      nullptr, qb, kb, vtb);
  attn_kernel<<<dim3(8, 64), 512, 0, stream>>>(qb, kb, vtb, ab);
  gemm256<1><<<256, 512, 0, stream>>>(ab, wprojT, bproj, 8192, 2048, 2048,
                                      out, nullptr, nullptr, nullptr);
}

// Round 14
// 546.413 us; speedup vs baseline: 4.4887x; 1.0963x over previous
//
#include <hip/hip_runtime.h>

// ---------------------------------------------------------------------------
// Fused MHA: qkv = x@Wqkv+b ; causal attention ; out = attn@Wproj+b
// B=4, T=2048, C=2048, H=16, D=128. fp32 in/out, bf16 MFMA internally.
// GEMM = R8 best-measured 256x256. attn = R13 + SWAPPED QK^T (T12: softmax
// reduction axis lane-local; 32 shfl -> 2, 16 scalar P-writes -> 4 b64).
// ---------------------------------------------------------------------------

typedef __bf16 bf16;
typedef __bf16 bf16x8 __attribute__((ext_vector_type(8)));
typedef __bf16 bf16x4 __attribute__((ext_vector_type(4)));
typedef float f32x4 __attribute__((ext_vector_type(4)));

__device__ __forceinline__ void gload_lds16(const void* g, void* l) {
  __builtin_amdgcn_global_load_lds(
      (const __attribute__((address_space(1))) void*)g,
      (__attribute__((address_space(3))) void*)l, 16, 0, 0);
}

// ---------------------------------------------------------------------------
// cast fp32 -> bf16, 8 elems/thread
__global__ __launch_bounds__(256) void cast_f32_bf16(
    const float* __restrict__ in, bf16* __restrict__ out, int n8) {
  int i = blockIdx.x * 256 + threadIdx.x;
  if (i >= n8) return;
  const float4* p = (const float4*)in + (size_t)i * 2;
  float4 a = p[0], b = p[1];
  bf16x8 o8 = {(bf16)a.x, (bf16)a.y, (bf16)a.z, (bf16)a.w,
               (bf16)b.x, (bf16)b.y, (bf16)b.z, (bf16)b.w};
  *(bf16x8*)(out + (size_t)i * 8) = o8;
}

// ---------------------------------------------------------------------------
// W [R][C] fp32  ->  WT [C][R] bf16   (32x32 LDS tile transpose)
__global__ __launch_bounds__(256) void transpose_cast(
    const float* __restrict__ in, bf16* __restrict__ out, int R, int C) {
  __shared__ bf16 tile[32][33];
  const int r0 = blockIdx.y * 32, c0 = blockIdx.x * 32;
  const int tid = threadIdx.x;
  const int c = tid & 31, r = tid >> 5;
#pragma unroll
  for (int rr = r; rr < 32; rr += 8)
    tile[rr][c] = (bf16)in[(size_t)(r0 + rr) * C + c0 + c];
  __syncthreads();
  const int oc = tid >> 3;           // out row within tile (0..31)
  const int ok = (tid & 7) * 4;      // out col chunk
  bf16x4 v;
#pragma unroll
  for (int j = 0; j < 4; ++j) v[j] = tile[ok + j][oc];
  *(bf16x4*)&out[(size_t)(c0 + oc) * R + r0 + ok] = v;
}

// ---------------------------------------------------------------------------
// 256x256 GEMM (R8 best-measured version, verbatim): C = A @ BT^T + bias.
template <int EPI>
__global__ __launch_bounds__(512, 2) void gemm256(
    const bf16* __restrict__ A, const bf16* __restrict__ BT,
    const float* __restrict__ bias, int M, int N, int K,
    float* __restrict__ outf, bf16* __restrict__ qb, bf16* __restrict__ kb,
    bf16* __restrict__ vtb) {
  __shared__ bf16 As[2][2][256 * 32];  // 64 KB
  __shared__ bf16 Bs[2][2][256 * 32];  // 64 KB
  const int tid = threadIdx.x;
  const int lane = tid & 63, w = tid >> 6;
  const int wm = w >> 2, wn = w & 3;
  const int lr = lane & 15, lg = lane >> 4;

  // bijective XCD swizzle (gridDim.x % 8 == 0 for both instantiations)
  const int nwg = gridDim.x, cpx = nwg >> 3;
  const int swz = (blockIdx.x & 7) * cpx + (blockIdx.x >> 3);
  const int ntx = N >> 8;  // tiles along N
  const int m0 = (swz / ntx) * 256, n0 = (swz % ntx) * 256;

  // stage one 16KB half-tile (kh, operand) of K-tile kt into dbuf d.
  // dest linear; source col pre-XOR'd by row-bit3 (both-sides swizzle).
  auto STAGE_H = [&](int d, int skh, int sisB, int kt) {
    const bf16* src = sisB ? BT : A;
    const int r0 = sisB ? n0 : m0;
    bf16* lb = sisB ? &Bs[d][skh][0] : &As[d][skh][0];
#pragma unroll
    for (int c = 0; c < 2; ++c) {
      const int chunk = w * 2 + c;                    // 0..15 (1KB chunks)
      const int row = chunk * 16 + (lane >> 2);       // 0..255
      const int col = ((lane & 3) * 8) ^ (((row >> 3) & 1) << 4);
      gload_lds16(src + (size_t)(r0 + row) * K + kt * 64 + skh * 32 + col,
                  (char*)lb + chunk * 1024);
    }
  };
  // fragment reads (swizzled): logical (row, lg*8..+7) of K-half kh
  auto LDA = [&](int d, int kh, int mi) -> bf16x8 {
    const int row = wm * 128 + mi * 16 + lr;
    return *(const bf16x8*)((const char*)&As[d][kh][0] +
                            ((row * 64 + lg * 16) ^ ((lr >> 3) << 5)));
  };
  auto LDB = [&](int d, int kh, int ni) -> bf16x8 {
    const int row = wn * 64 + ni * 16 + lr;
    return *(const bf16x8*)((const char*)&Bs[d][kh][0] +
                            ((row * 64 + lg * 16) ^ ((lr >> 3) << 5)));
  };

  f32x4 acc[8][4] = {};
  const int NT = K >> 6;

  // one half-K compute: 12 ds_read + 32 MFMA, compiler-scheduled
  auto COMPUTE = [&](int d, int kh) {
    bf16x8 af[8], bfr[4];
#pragma unroll
    for (int mi = 0; mi < 8; ++mi) af[mi] = LDA(d, kh, mi);
#pragma unroll
    for (int ni = 0; ni < 4; ++ni) bfr[ni] = LDB(d, kh, ni);
#pragma unroll
    for (int mi = 0; mi < 8; ++mi)
#pragma unroll
      for (int ni = 0; ni < 4; ++ni)
        acc[mi][ni] = __builtin_amdgcn_mfma_f32_16x16x32_bf16(
            af[mi], bfr[ni], acc[mi][ni], 0, 0, 0);
  };

  // prologue: stage tile 0 fully, drain, sync
  STAGE_H(0, 0, 0, 0);
  STAGE_H(0, 0, 1, 0);
  STAGE_H(0, 1, 0, 0);
  STAGE_H(0, 1, 1, 0);
  asm volatile("s_waitcnt vmcnt(0)" ::: "memory");
  __builtin_amdgcn_s_barrier();

  for (int t = 0; t < NT; ++t) {
    const int cur = t & 1;
    if (t + 1 < NT) {  // issue next tile's 8 loads; they fly under 64 MFMA
      STAGE_H(cur ^ 1, 0, 0, t + 1);
      STAGE_H(cur ^ 1, 0, 1, t + 1);
      STAGE_H(cur ^ 1, 1, 0, t + 1);
      STAGE_H(cur ^ 1, 1, 1, t + 1);
    }
    __builtin_amdgcn_s_setprio(1);
    COMPUTE(cur, 0);
    COMPUTE(cur, 1);
    __builtin_amdgcn_s_setprio(0);
    asm volatile("s_waitcnt vmcnt(0)" ::: "memory");
    __builtin_amdgcn_s_barrier();  // buf cur free + t+1 data visible
  }

  // epilogue: C/D layout col=lane&15, row=(lane>>4)*4+r  [m89/m91]
#pragma unroll
  for (int mi = 0; mi < 8; ++mi) {
    const int mbase = m0 + wm * 128 + mi * 16 + lg * 4;
#pragma unroll
    for (int ni = 0; ni < 4; ++ni) {
      const int n = n0 + wn * 64 + ni * 16 + lr;
      const float bv = bias[n];
      if (EPI == 1) {
#pragma unroll
        for (int r = 0; r < 4; ++r)
          outf[(size_t)(mbase + r) * N + n] = acc[mi][ni][r] + bv;
      } else {
        const int which = n >> 11;           // 0=q 1=k 2=v
        const int cc = n & 2047, h = cc >> 7, dd = cc & 127;
        const int b = mbase >> 11, t0 = mbase & 2047;  // 4-row group never
        const int bh = b * 16 + h;                     // crosses b boundary
        if (which == 2) {
          bf16x4 pk;
#pragma unroll
          for (int r = 0; r < 4; ++r) pk[r] = (bf16)(acc[mi][ni][r] + bv);
          *(bf16x4*)&vtb[((size_t)bh * 128 + dd) * 2048 + t0] = pk;
        } else {
          bf16* dst = (which == 0) ? qb : kb;
#pragma unroll
          for (int r = 0; r < 4; ++r)
            dst[((size_t)bh * 2048 + t0 + r) * 128 + dd] =
                (bf16)(acc[mi][ni][r] + bv);
        }
      }
    }
  }
}

// ---------------------------------------------------------------------------
// Flash attention, causal, WORK-BALANCED pairing, 80 KB LDS (2 blocks/CU).
// SWAPPED QK^T (this round): s[j] = mfma(kf, qf, s) -> lane holds
// S[k = j*16+lg*4+r][q = lr]: each lane owns 16 scores of ONE q-row, so
// row max/sum are in-register trees + 2 shfl_xor (^16, ^32). A/B frags have
// symmetric layouts (row/col = lane&15, k = 8*lg+e) so kf/qf reads are
// UNCHANGED. P written as 4 x ds_write_b64 (bf16x4 runs, 2-way bank = free)
// into the same swizzled Ps layout the (unchanged) PV path reads.
// O rows have q = lg*4+r, softmax state has q = lr -> alpha/lst fetched via
// __shfl((lane&48)|(lg*4+r)) in the (rare) rescale branch and the epilogue.
__global__ __launch_bounds__(512) void attn_kernel(
    const bf16* __restrict__ qb, const bf16* __restrict__ kb,
    const bf16* __restrict__ vtb, bf16* __restrict__ ob) {
  __shared__ bf16 Ks[2][64 * 128];  // 32 KB, swizzled
  __shared__ bf16 Vs[2][128 * 64];  // 32 KB, swizzled
  __shared__ bf16 Ps[8][16 * 64];   // 16 KB, swizzled  -> total 80 KB
  const int tid = threadIdx.x, lane = tid & 63, w = tid >> 6;
  const int bh = blockIdx.y;
  const int qtA = blockIdx.x;            // 0..7
  const int qtB = 15 - qtA;              // 8..15
  const int qt_w = (w < 4) ? qtA : qtB;  // this wave's q-tile
  const int wq = w & 3;                  // wave slot within its q-tile
  const int lr = lane & 15, lg = lane >> 4;
  const int q0 = qt_w * 128;
  const size_t base = (size_t)bh * (2048 * 128);
  const int rswz = (lr & 7) << 3;  // row-XOR (element domain)

  // hoist Q frags; fold (1/sqrt(D))*log2(e) so softmax runs in exp2 domain
  const float qscale = 0.08838834764831845f * 1.4426950408889634f;
  bf16x8 qf[2][4];
#pragma unroll
  for (int g = 0; g < 2; ++g) {
    const bf16* qp =
        qb + base + (size_t)(q0 + g * 64 + wq * 16 + lr) * 128 + lg * 8;
#pragma unroll
    for (int kk = 0; kk < 4; ++kk) {
      bf16x8 t = *(const bf16x8*)(qp + kk * 32);
#pragma unroll
      for (int e = 0; e < 8; ++e) t[e] = (bf16)((float)t[e] * qscale);
      qf[g][kk] = t;
    }
  }

  f32x4 o[2][8] = {};
  float mst[2] = {-1e30f, -1e30f};  // running max for q = lr (exp2 domain)
  float lst[2] = {0.f, 0.f};        // running sum for q = lr

  // stage tile kt into buffer bsel: 512 threads x 2 sweeps x (K+V) -> 4
  // gload_lds per thread. dest linear per wave; source col pre-XOR'd.
  auto STAGE = [&](int bsel, int kt) {
#pragma unroll
    for (int c = 0; c < 2; ++c) {
      const int L = w * 1024 + c * 8192 + lane * 16;  // byte offset in 16KB
      {  // K tile rows 256B
        const int row = L >> 8, ce = (L & 255) >> 1;
        gload_lds16(kb + base + (size_t)(kt * 64 + row) * 128 +
                        (ce ^ ((row & 7) << 3)),
                    (char*)Ks[bsel] + w * 1024 + c * 8192);
      }
      {  // V^T tile rows 128B
        const int d = L >> 7, ce = (L & 127) >> 1;
        gload_lds16(vtb + base + (size_t)d * 2048 + kt * 64 +
                        (ce ^ ((d & 7) << 3)),
                    (char*)Vs[bsel] + w * 1024 + c * 8192);
      }
    }
  };

  const int nst = 2 * qtB + 2;  // staged tiles (covers A's range too)
  STAGE(0, 0);                  // 4 outstanding; drained by iter 0's vmcnt(4)
  for (int kt = 0; kt < nst; ++kt) {
    const int cur = kt & 1;
    if (kt + 1 < nst) {
      STAGE(cur ^ 1, kt + 1);  // 4 more in flight
      asm volatile("s_waitcnt vmcnt(4)" ::: "memory");  // tile kt landed
    } else {
      asm volatile("s_waitcnt vmcnt(0)" ::: "memory");
    }
    __builtin_amdgcn_s_barrier();  // all waves' staging of kt visible
    __builtin_amdgcn_sched_barrier(0);

    const bf16* Kc = Ks[cur];
    const bf16* Vc = Vs[cur];
#pragma unroll
    for (int g = 0; g < 2; ++g) {
      if (kt > 2 * qt_w + g) continue;  // wave-uniform: past this group's diag
      const bool diag = (kt == 2 * qt_w + g);

      // S' = K Q^T (swapped operands; same frag reads as before)
      f32x4 s[4] = {};
      __builtin_amdgcn_s_setprio(1);
#pragma unroll
      for (int kk = 0; kk < 4; ++kk)
#pragma unroll
        for (int j = 0; j < 4; ++j) {
          const bf16x8 kf = *(const bf16x8*)&Kc[(j * 16 + lr) * 128 +
                                               ((kk * 32 + lg * 8) ^ rswz)];
          s[j] = __builtin_amdgcn_mfma_f32_16x16x32_bf16(kf, qf[g][kk], s[j],
                                                         0, 0, 0);
        }
      __builtin_amdgcn_s_setprio(0);

      if (diag) {  // mask k > q: k = j*16+lg*4+r, q = wq*16+lr (tile-rel)
        const int qq = wq * 16 + lr;
#pragma unroll
        for (int j = 0; j < 4; ++j)
#pragma unroll
          for (int r = 0; r < 4; ++r)
            if (j * 16 + lg * 4 + r > qq) s[j][r] = -1e30f;
      }

      // in-lane softmax for q = lr (16 values in this lane)
      float pm;
      {
        float a0 = fmaxf(fmaxf(s[0][0], s[0][1]), fmaxf(s[0][2], s[0][3]));
        float a1 = fmaxf(fmaxf(s[1][0], s[1][1]), fmaxf(s[1][2], s[1][3]));
        float a2 = fmaxf(fmaxf(s[2][0], s[2][1]), fmaxf(s[2][2], s[2][3]));
        float a3 = fmaxf(fmaxf(s[3][0], s[3][1]), fmaxf(s[3][2], s[3][3]));
        pm = fmaxf(fmaxf(a0, a1), fmaxf(a2, a3));
      }
      pm = fmaxf(pm, __shfl_xor(pm, 16));
      pm = fmaxf(pm, __shfl_xor(pm, 32));

      // T13 defer-max: rescale only when some row's max grew by >8
      if (__any(pm > mst[g] + 8.0f)) {
        const float mnew = fmaxf(mst[g], pm);
        const float alpha = __builtin_amdgcn_exp2f(mst[g] - mnew);
        mst[g] = mnew;
        lst[g] *= alpha;
#pragma unroll
        for (int r = 0; r < 4; ++r) {  // o rows: q = lg*4+r
          const float av = __shfl(alpha, (lane & 48) | (lg * 4 + r));
#pragma unroll
          for (int n = 0; n < 8; ++n) o[g][n][r] *= av;
        }
      }

      // P = exp2(s - m); in-lane sum + 2 shfl; write 4 x b64 to Ps
      float rs = 0.f;
#pragma unroll
      for (int j = 0; j < 4; ++j)
#pragma unroll
        for (int r = 0; r < 4; ++r) {
          const float p = __builtin_amdgcn_exp2f(s[j][r] - mst[g]);
          s[j][r] = p;
          rs += p;
        }
      rs += __shfl_xor(rs, 16);
      rs += __shfl_xor(rs, 32);
      lst[g] += rs;
#pragma unroll
      for (int j = 0; j < 4; ++j) {
        bf16x4 pw;
#pragma unroll
        for (int r = 0; r < 4; ++r) pw[r] = (bf16)s[j][r];
        const int k0 = j * 16 + lg * 4;  // 4-aligned; XOR flips bits 3-5 only
        *(bf16x4*)&Ps[w][lr * 64 + (k0 ^ rswz)] = pw;
      }

      // P @ V (unchanged): A-frag P rows = lr, B-frag V^T cols = lr
      bf16x8 pf[2];
#pragma unroll
      for (int kk = 0; kk < 2; ++kk)
        pf[kk] = *(const bf16x8*)&Ps[w][lr * 64 +
                                       ((kk * 32 + lg * 8) ^ rswz)];
      __builtin_amdgcn_s_setprio(1);
#pragma unroll
      for (int n = 0; n < 8; ++n)
#pragma unroll
        for (int kk = 0; kk < 2; ++kk) {
          const bf16x8 vf = *(const bf16x8*)&Vc[(n * 16 + lr) * 64 +
                                               ((kk * 32 + lg * 8) ^ rswz)];
          o[g][n] = __builtin_amdgcn_mfma_f32_16x16x32_bf16(pf[kk], vf,
                                                            o[g][n], 0, 0, 0);
        }
      __builtin_amdgcn_s_setprio(0);
    }
    __builtin_amdgcn_sched_barrier(0);
    __builtin_amdgcn_s_barrier();  // all reads of buf cur done before next
    __builtin_amdgcn_sched_barrier(0);  // STAGE overwrites it
  }

  // write attn-out as bf16 [B*T][C]; lst holds q=lr, o rows are q=lg*4+r
  const int b = bh >> 4, h = bh & 15;
#pragma unroll
  for (int g = 0; g < 2; ++g)
#pragma unroll
    for (int r = 0; r < 4; ++r) {
      const float inv = 1.0f / __shfl(lst[g], (lane & 48) | (lg * 4 + r));
      const int t = q0 + g * 64 + wq * 16 + lg * 4 + r;
      bf16* dst = ob + ((size_t)(b * 2048 + t)) * 2048 + h * 128;
#pragma unroll
      for (int n = 0; n < 8; ++n) dst[n * 16 + lr] = (bf16)(o[g][n][r] * inv);
    }
}

// ---------------------------------------------------------------------------
extern "C" void kernel_launch(void* const* d_in, const int* in_sizes, int n_in,
                              void* d_out, int out_size, void* d_ws,
                              size_t ws_size, hipStream_t stream) {
  const float* x = (const float*)d_in[0];      // [4,2048,2048]
  const float* Wqkv = (const float*)d_in[1];   // [2048,6144]
  const float* bqkv = (const float*)d_in[2];   // [6144]
  const float* Wproj = (const float*)d_in[3];  // [2048,2048]
  const float* bproj = (const float*)d_in[4];  // [2048]
  float* out = (float*)d_out;                  // [8192,2048] fp32

  char* ws = (char*)d_ws;  // needs ~192 MiB
  bf16* xb     = (bf16*)(ws);                  // 33554432 B  x bf16
  bf16* wqkvT  = (bf16*)(ws + 33554432);       // 25165824 B  Wqkv^T
  bf16* wprojT = (bf16*)(ws + 58720256);       //  8388608 B  Wproj^T
  bf16* qb     = (bf16*)(ws + 67108864);       // 33554432 B  Q [BH][T][D]
  bf16* kb     = (bf16*)(ws + 100663296);      // 33554432 B  K [BH][T][D]
  bf16* vtb    = (bf16*)(ws + 134217728);      // 33554432 B  V^T [BH][D][T]
  bf16* ab     = (bf16*)(ws + 167772160);      // 33554432 B  attn out bf16

  cast_f32_bf16<<<8192, 256, 0, stream>>>(x, xb, 2097152);
  transpose_cast<<<dim3(192, 64), 256, 0, stream>>>(Wqkv, wqkvT, 2048, 6144);
  transpose_cast<<<dim3(64, 64), 256, 0, stream>>>(Wproj, wprojT, 2048, 2048);
  gemm256<0><<<768, 512, 0, stream>>>(xb, wqkvT, bqkv, 8192, 6144, 2048,
                                      nullptr, qb, kb, vtb);
  attn_kernel<<<dim3(8, 64), 512, 0, stream>>>(qb, kb, vtb, ab);
  gemm256<1><<<256, 512, 0, stream>>>(ab, wprojT, bproj, 8192, 2048, 2048,
                                      out, nullptr, nullptr, nullptr);
}

// Round 15
// 522.555 us; speedup vs baseline: 4.6936x; 1.0457x over previous
//
#include <hip/hip_runtime.h>

// ---------------------------------------------------------------------------
// Fused MHA: qkv = x@Wqkv+b ; causal attention ; out = attn@Wproj+b
// B=4, T=2048, C=2048, H=16, D=128. fp32 in/out, bf16 MFMA internally.
// GEMM = R8 best-measured 256x256 (frozen). attn = R14 swapped-QK + KVBLK=128
// (halved per-tile sync/softmax overhead). transpose_cast = vectorized 64x64.
// ---------------------------------------------------------------------------

typedef __bf16 bf16;
typedef __bf16 bf16x8 __attribute__((ext_vector_type(8)));
typedef __bf16 bf16x4 __attribute__((ext_vector_type(4)));
typedef float f32x4 __attribute__((ext_vector_type(4)));

__device__ __forceinline__ void gload_lds16(const void* g, void* l) {
  __builtin_amdgcn_global_load_lds(
      (const __attribute__((address_space(1))) void*)g,
      (__attribute__((address_space(3))) void*)l, 16, 0, 0);
}

// ---------------------------------------------------------------------------
// cast fp32 -> bf16, 8 elems/thread (unchanged)
__global__ __launch_bounds__(256) void cast_f32_bf16(
    const float* __restrict__ in, bf16* __restrict__ out, int n8) {
  int i = blockIdx.x * 256 + threadIdx.x;
  if (i >= n8) return;
  const float4* p = (const float4*)in + (size_t)i * 2;
  float4 a = p[0], b = p[1];
  bf16x8 o8 = {(bf16)a.x, (bf16)a.y, (bf16)a.z, (bf16)a.w,
               (bf16)b.x, (bf16)b.y, (bf16)b.z, (bf16)b.w};
  *(bf16x8*)(out + (size_t)i * 8) = o8;
}

// ---------------------------------------------------------------------------
// W [R][C] fp32 -> WT [C][R] bf16. 64x64 tile, 256 thr, vectorized (G13):
// float4 x4 loads, XOR-swizzled LDS (elem ^ (row&7)<<3), bf16x8 x2 stores.
__global__ __launch_bounds__(256) void transpose_cast(
    const float* __restrict__ in, bf16* __restrict__ out, int R, int C) {
  __shared__ bf16 tile[64 * 64];  // 8 KB, swizzled
  const int r0 = blockIdx.y * 64, c0 = blockIdx.x * 64;
  const int t = threadIdx.x;
  const int ri = t >> 2, cseg = (t & 3) * 16;
  const float4* src =
      (const float4*)&in[(size_t)(r0 + ri) * C + c0 + cseg];
  float4 f0 = src[0], f1 = src[1], f2 = src[2], f3 = src[3];
  bf16x8 h0 = {(bf16)f0.x, (bf16)f0.y, (bf16)f0.z, (bf16)f0.w,
               (bf16)f1.x, (bf16)f1.y, (bf16)f1.z, (bf16)f1.w};
  bf16x8 h1 = {(bf16)f2.x, (bf16)f2.y, (bf16)f2.z, (bf16)f2.w,
               (bf16)f3.x, (bf16)f3.y, (bf16)f3.z, (bf16)f3.w};
  const int kx = (ri & 7) << 3;
  *(bf16x8*)&tile[ri * 64 + (cseg ^ kx)] = h0;
  *(bf16x8*)&tile[ri * 64 + ((cseg + 8) ^ kx)] = h1;
  __syncthreads();
  const int oj = t >> 2, rseg = (t & 3) * 16;
  bf16 v[16];
#pragma unroll
  for (int i = 0; i < 16; ++i) {
    const int rr = rseg + i;
    v[i] = tile[rr * 64 + (oj ^ ((rr & 7) << 3))];
  }
  bf16* dst = &out[(size_t)(c0 + oj) * R + r0 + rseg];
  *(bf16x8*)dst = *(bf16x8*)&v[0];
  *(bf16x8*)(dst + 8) = *(bf16x8*)&v[8];
}

// ---------------------------------------------------------------------------
// 256x256 GEMM (R8 best-measured version, verbatim): C = A @ BT^T + bias.
template <int EPI>
__global__ __launch_bounds__(512, 2) void gemm256(
    const bf16* __restrict__ A, const bf16* __restrict__ BT,
    const float* __restrict__ bias, int M, int N, int K,
    float* __restrict__ outf, bf16* __restrict__ qb, bf16* __restrict__ kb,
    bf16* __restrict__ vtb) {
  __shared__ bf16 As[2][2][256 * 32];  // 64 KB
  __shared__ bf16 Bs[2][2][256 * 32];  // 64 KB
  const int tid = threadIdx.x;
  const int lane = tid & 63, w = tid >> 6;
  const int wm = w >> 2, wn = w & 3;
  const int lr = lane & 15, lg = lane >> 4;

  // bijective XCD swizzle (gridDim.x % 8 == 0 for both instantiations)
  const int nwg = gridDim.x, cpx = nwg >> 3;
  const int swz = (blockIdx.x & 7) * cpx + (blockIdx.x >> 3);
  const int ntx = N >> 8;  // tiles along N
  const int m0 = (swz / ntx) * 256, n0 = (swz % ntx) * 256;

  // stage one 16KB half-tile (kh, operand) of K-tile kt into dbuf d.
  // dest linear; source col pre-XOR'd by row-bit3 (both-sides swizzle).
  auto STAGE_H = [&](int d, int skh, int sisB, int kt) {
    const bf16* src = sisB ? BT : A;
    const int r0 = sisB ? n0 : m0;
    bf16* lb = sisB ? &Bs[d][skh][0] : &As[d][skh][0];
#pragma unroll
    for (int c = 0; c < 2; ++c) {
      const int chunk = w * 2 + c;                    // 0..15 (1KB chunks)
      const int row = chunk * 16 + (lane >> 2);       // 0..255
      const int col = ((lane & 3) * 8) ^ (((row >> 3) & 1) << 4);
      gload_lds16(src + (size_t)(r0 + row) * K + kt * 64 + skh * 32 + col,
                  (char*)lb + chunk * 1024);
    }
  };
  // fragment reads (swizzled): logical (row, lg*8..+7) of K-half kh
  auto LDA = [&](int d, int kh, int mi) -> bf16x8 {
    const int row = wm * 128 + mi * 16 + lr;
    return *(const bf16x8*)((const char*)&As[d][kh][0] +
                            ((row * 64 + lg * 16) ^ ((lr >> 3) << 5)));
  };
  auto LDB = [&](int d, int kh, int ni) -> bf16x8 {
    const int row = wn * 64 + ni * 16 + lr;
    return *(const bf16x8*)((const char*)&Bs[d][kh][0] +
                            ((row * 64 + lg * 16) ^ ((lr >> 3) << 5)));
  };

  f32x4 acc[8][4] = {};
  const int NT = K >> 6;

  // one half-K compute: 12 ds_read + 32 MFMA, compiler-scheduled
  auto COMPUTE = [&](int d, int kh) {
    bf16x8 af[8], bfr[4];
#pragma unroll
    for (int mi = 0; mi < 8; ++mi) af[mi] = LDA(d, kh, mi);
#pragma unroll
    for (int ni = 0; ni < 4; ++ni) bfr[ni] = LDB(d, kh, ni);
#pragma unroll
    for (int mi = 0; mi < 8; ++mi)
#pragma unroll
      for (int ni = 0; ni < 4; ++ni)
        acc[mi][ni] = __builtin_amdgcn_mfma_f32_16x16x32_bf16(
            af[mi], bfr[ni], acc[mi][ni], 0, 0, 0);
  };

  // prologue: stage tile 0 fully, drain, sync
  STAGE_H(0, 0, 0, 0);
  STAGE_H(0, 0, 1, 0);
  STAGE_H(0, 1, 0, 0);
  STAGE_H(0, 1, 1, 0);
  asm volatile("s_waitcnt vmcnt(0)" ::: "memory");
  __builtin_amdgcn_s_barrier();

  for (int t = 0; t < NT; ++t) {
    const int cur = t & 1;
    if (t + 1 < NT) {  // issue next tile's 8 loads; they fly under 64 MFMA
      STAGE_H(cur ^ 1, 0, 0, t + 1);
      STAGE_H(cur ^ 1, 0, 1, t + 1);
      STAGE_H(cur ^ 1, 1, 0, t + 1);
      STAGE_H(cur ^ 1, 1, 1, t + 1);
    }
    __builtin_amdgcn_s_setprio(1);
    COMPUTE(cur, 0);
    COMPUTE(cur, 1);
    __builtin_amdgcn_s_setprio(0);
    asm volatile("s_waitcnt vmcnt(0)" ::: "memory");
    __builtin_amdgcn_s_barrier();  // buf cur free + t+1 data visible
  }

  // epilogue: C/D layout col=lane&15, row=(lane>>4)*4+r  [m89/m91]
#pragma unroll
  for (int mi = 0; mi < 8; ++mi) {
    const int mbase = m0 + wm * 128 + mi * 16 + lg * 4;
#pragma unroll
    for (int ni = 0; ni < 4; ++ni) {
      const int n = n0 + wn * 64 + ni * 16 + lr;
      const float bv = bias[n];
      if (EPI == 1) {
#pragma unroll
        for (int r = 0; r < 4; ++r)
          outf[(size_t)(mbase + r) * N + n] = acc[mi][ni][r] + bv;
      } else {
        const int which = n >> 11;           // 0=q 1=k 2=v
        const int cc = n & 2047, h = cc >> 7, dd = cc & 127;
        const int b = mbase >> 11, t0 = mbase & 2047;  // 4-row group never
        const int bh = b * 16 + h;                     // crosses b boundary
        if (which == 2) {
          bf16x4 pk;
#pragma unroll
          for (int r = 0; r < 4; ++r) pk[r] = (bf16)(acc[mi][ni][r] + bv);
          *(bf16x4*)&vtb[((size_t)bh * 128 + dd) * 2048 + t0] = pk;
        } else {
          bf16* dst = (which == 0) ? qb : kb;
#pragma unroll
          for (int r = 0; r < 4; ++r)
            dst[((size_t)bh * 2048 + t0 + r) * 128 + dd] =
                (bf16)(acc[mi][ni][r] + bv);
        }
      }
    }
  }
}

// ---------------------------------------------------------------------------
// Flash attention, causal, WORK-BALANCED pairing, SWAPPED QK^T, KVBLK=128.
// grid = (8, B*H), 512 thr. Block x owns q-tiles qtA=x (waves 0-3), qtB=15-x
// (waves 4-7); nst = qtB+1 128-wide KV tiles (A-waves skip tiles past their
// diagonal; totals balanced across blocks). Per-tile sync costs (2 barriers,
// vmcnt, shfl pairs, defer-max) amortize over 2x the KV work vs KVBLK=64.
// LDS 144 KB: Ks[2][128x128] 64K + Vs[2][128x128] 64K + Ps[8][16x64] 16K.
// P->PV runs in two sequential K=64 halves through the per-wave Ps buffer
// (within-wave ds ordering; no extra barriers). Swapped-QK: lane holds
// S[k=j*16+lg*4+r][q=lr], j=0..7; softmax in-lane + 2 shfl_xor.
__global__ __launch_bounds__(512) void attn_kernel(
    const bf16* __restrict__ qb, const bf16* __restrict__ kb,
    const bf16* __restrict__ vtb, bf16* __restrict__ ob) {
  __shared__ bf16 Ks[2][128 * 128];  // 64 KB, swizzled
  __shared__ bf16 Vs[2][128 * 128];  // 64 KB, swizzled ([d][t])
  __shared__ bf16 Ps[8][16 * 64];    // 16 KB, swizzled
  const int tid = threadIdx.x, lane = tid & 63, w = tid >> 6;
  const int bh = blockIdx.y;
  const int qtA = blockIdx.x;            // 0..7
  const int qtB = 15 - qtA;              // 8..15
  const int qt_w = (w < 4) ? qtA : qtB;  // this wave's q-tile
  const int wq = w & 3;                  // wave slot within its q-tile
  const int lr = lane & 15, lg = lane >> 4;
  const int q0 = qt_w * 128;
  const size_t base = (size_t)bh * (2048 * 128);
  const int rswz = (lr & 7) << 3;  // row-XOR (element domain)

  // hoist Q frags; fold (1/sqrt(D))*log2(e) so softmax runs in exp2 domain
  const float qscale = 0.08838834764831845f * 1.4426950408889634f;
  bf16x8 qf[2][4];
#pragma unroll
  for (int g = 0; g < 2; ++g) {
    const bf16* qp =
        qb + base + (size_t)(q0 + g * 64 + wq * 16 + lr) * 128 + lg * 8;
#pragma unroll
    for (int kk = 0; kk < 4; ++kk) {
      bf16x8 t = *(const bf16x8*)(qp + kk * 32);
#pragma unroll
      for (int e = 0; e < 8; ++e) t[e] = (bf16)((float)t[e] * qscale);
      qf[g][kk] = t;
    }
  }

  f32x4 o[2][8] = {};
  float mst[2] = {-1e30f, -1e30f};  // running max for q = lr (exp2 domain)
  float lst[2] = {0.f, 0.f};        // running sum for q = lr

  // stage 128-wide tile kt: K 32KB + V 32KB; 8 gload_lds/thread.
  // dest linear; source col pre-XOR'd by row-bit3 (both-sides swizzle).
  auto STAGE = [&](int bsel, int kt) {
#pragma unroll
    for (int c = 0; c < 4; ++c) {
      const int off = w * 1024 + c * 8192 + lane * 16;  // byte off in 32KB
      const int row = off >> 8, ce = (off & 255) >> 1;  // 256B rows
      gload_lds16(kb + base + (size_t)(kt * 128 + row) * 128 +
                      (ce ^ ((row & 7) << 3)),
                  (char*)Ks[bsel] + w * 1024 + c * 8192);
      gload_lds16(vtb + base + (size_t)row * 2048 + kt * 128 +
                      (ce ^ ((row & 7) << 3)),
                  (char*)Vs[bsel] + w * 1024 + c * 8192);
    }
  };

  const int nst = qtB + 1;  // 128-wide tiles (covers A's range too)
  STAGE(0, 0);              // 8 outstanding
  for (int kt = 0; kt < nst; ++kt) {
    const int cur = kt & 1;
    if (kt + 1 < nst) {
      STAGE(cur ^ 1, kt + 1);  // 8 more in flight
      asm volatile("s_waitcnt vmcnt(8)" ::: "memory");  // tile kt landed
    } else {
      asm volatile("s_waitcnt vmcnt(0)" ::: "memory");
    }
    __builtin_amdgcn_s_barrier();  // all waves' staging of kt visible
    __builtin_amdgcn_sched_barrier(0);

    const bf16* Kc = Ks[cur];
    const bf16* Vc = Vs[cur];
#pragma unroll
    for (int g = 0; g < 2; ++g) {
      const int gb = 2 * qt_w + g;       // global 64-row q-group index
      const int gbrel = gb - 2 * kt;     // tile covers k-blocks 2kt,2kt+1
      if (gbrel < 0) continue;           // wave-uniform: past diagonal

      // S' = K Q^T (swapped): s[j], k_rel = j*16+lg*4+r (0..127), q = lr
      f32x4 s[8] = {};
      __builtin_amdgcn_s_setprio(1);
#pragma unroll
      for (int kk = 0; kk < 4; ++kk)
#pragma unroll
        for (int j = 0; j < 8; ++j) {
          const bf16x8 kf = *(const bf16x8*)&Kc[(j * 16 + lr) * 128 +
                                               ((kk * 32 + lg * 8) ^ rswz)];
          s[j] = __builtin_amdgcn_mfma_f32_16x16x32_bf16(kf, qf[g][kk], s[j],
                                                         0, 0, 0);
        }
      __builtin_amdgcn_s_setprio(0);

      if (gbrel <= 1) {  // diagonal lives in this tile
        const int qq = gbrel * 64 + wq * 16 + lr;  // diag threshold (k units)
#pragma unroll
        for (int j = 0; j < 8; ++j)
#pragma unroll
          for (int r = 0; r < 4; ++r)
            if (j * 16 + lg * 4 + r > qq) s[j][r] = -1e30f;
      }

      // in-lane softmax for q = lr (32 values in this lane)
      float pm;
      {
        float a0 = -1e30f, a1 = -1e30f;
#pragma unroll
        for (int j = 0; j < 8; j += 2) {
          a0 = fmaxf(a0, fmaxf(fmaxf(s[j][0], s[j][1]),
                               fmaxf(s[j][2], s[j][3])));
          a1 = fmaxf(a1, fmaxf(fmaxf(s[j + 1][0], s[j + 1][1]),
                               fmaxf(s[j + 1][2], s[j + 1][3])));
        }
        pm = fmaxf(a0, a1);
      }
      pm = fmaxf(pm, __shfl_xor(pm, 16));
      pm = fmaxf(pm, __shfl_xor(pm, 32));

      // T13 defer-max: rescale only when some row's max grew by >8
      if (__any(pm > mst[g] + 8.0f)) {
        const float mnew = fmaxf(mst[g], pm);
        const float alpha = __builtin_amdgcn_exp2f(mst[g] - mnew);
        mst[g] = mnew;
        lst[g] *= alpha;
#pragma unroll
        for (int r = 0; r < 4; ++r) {  // o rows: q = lg*4+r
          const float av = __shfl(alpha, (lane & 48) | (lg * 4 + r));
#pragma unroll
          for (int n = 0; n < 8; ++n) o[g][n][r] *= av;
        }
      }

      // P = exp2(s - m); in-lane sum + 2 shfl
      float rs = 0.f;
#pragma unroll
      for (int j = 0; j < 8; ++j)
#pragma unroll
        for (int r = 0; r < 4; ++r) {
          const float p = __builtin_amdgcn_exp2f(s[j][r] - mst[g]);
          s[j][r] = p;
          rs += p;
        }
      rs += __shfl_xor(rs, 16);
      rs += __shfl_xor(rs, 32);
      lst[g] += rs;

      // P @ V in two K=64 halves through the per-wave Ps buffer
      __builtin_amdgcn_s_setprio(1);
#pragma unroll
      for (int h = 0; h < 2; ++h) {
#pragma unroll
        for (int j2 = 0; j2 < 4; ++j2) {
          const int j = h * 4 + j2;
          bf16x4 pw;
#pragma unroll
          for (int r = 0; r < 4; ++r) pw[r] = (bf16)s[j][r];
          *(bf16x4*)&Ps[w][lr * 64 + ((j2 * 16 + lg * 4) ^ rswz)] = pw;
        }
        bf16x8 pf[2];
#pragma unroll
        for (int kk = 0; kk < 2; ++kk)
          pf[kk] = *(const bf16x8*)&Ps[w][lr * 64 +
                                         ((kk * 32 + lg * 8) ^ rswz)];
#pragma unroll
        for (int n = 0; n < 8; ++n)
#pragma unroll
          for (int kk = 0; kk < 2; ++kk) {
            const bf16x8 vf = *(const bf16x8*)&Vc[(n * 16 + lr) * 128 +
                                                 ((h * 64 + kk * 32 +
                                                   lg * 8) ^ rswz)];
            o[g][n] = __builtin_amdgcn_mfma_f32_16x16x32_bf16(
                pf[kk], vf, o[g][n], 0, 0, 0);
          }
      }
      __builtin_amdgcn_s_setprio(0);
    }
    __builtin_amdgcn_sched_barrier(0);
    __builtin_amdgcn_s_barrier();  // all reads of buf cur done before next
    __builtin_amdgcn_sched_barrier(0);  // STAGE overwrites it
  }

  // write attn-out as bf16 [B*T][C]; lst holds q=lr, o rows are q=lg*4+r
  const int b = bh >> 4, h = bh & 15;
#pragma unroll
  for (int g = 0; g < 2; ++g)
#pragma unroll
    for (int r = 0; r < 4; ++r) {
      const float inv = 1.0f / __shfl(lst[g], (lane & 48) | (lg * 4 + r));
      const int t = q0 + g * 64 + wq * 16 + lg * 4 + r;
      bf16* dst = ob + ((size_t)(b * 2048 + t)) * 2048 + h * 128;
#pragma unroll
      for (int n = 0; n < 8; ++n) dst[n * 16 + lr] = (bf16)(o[g][n][r] * inv);
    }
}

// ---------------------------------------------------------------------------
extern "C" void kernel_launch(void* const* d_in, const int* in_sizes, int n_in,
                              void* d_out, int out_size, void* d_ws,
                              size_t ws_size, hipStream_t stream) {
  const float* x = (const float*)d_in[0];      // [4,2048,2048]
  const float* Wqkv = (const float*)d_in[1];   // [2048,6144]
  const float* bqkv = (const float*)d_in[2];   // [6144]
  const float* Wproj = (const float*)d_in[3];  // [2048,2048]
  const float* bproj = (const float*)d_in[4];  // [2048]
  float* out = (float*)d_out;                  // [8192,2048] fp32

  char* ws = (char*)d_ws;  // needs ~192 MiB
  bf16* xb     = (bf16*)(ws);                  // 33554432 B  x bf16
  bf16* wqkvT  = (bf16*)(ws + 33554432);       // 25165824 B  Wqkv^T
  bf16* wprojT = (bf16*)(ws + 58720256);       //  8388608 B  Wproj^T
  bf16* qb     = (bf16*)(ws + 67108864);       // 33554432 B  Q [BH][T][D]
  bf16* kb     = (bf16*)(ws + 100663296);      // 33554432 B  K [BH][T][D]
  bf16* vtb    = (bf16*)(ws + 134217728);      // 33554432 B  V^T [BH][D][T]
  bf16* ab     = (bf16*)(ws + 167772160);      // 33554432 B  attn out bf16

  cast_f32_bf16<<<8192, 256, 0, stream>>>(x, xb, 2097152);
  transpose_cast<<<dim3(96, 32), 256, 0, stream>>>(Wqkv, wqkvT, 2048, 6144);
  transpose_cast<<<dim3(32, 32), 256, 0, stream>>>(Wproj, wprojT, 2048, 2048);
  gemm256<0><<<768, 512, 0, stream>>>(xb, wqkvT, bqkv, 8192, 6144, 2048,
                                      nullptr, qb, kb, vtb);
  attn_kernel<<<dim3(8, 64), 512, 0, stream>>>(qb, kb, vtb, ab);
  gemm256<1><<<256, 512, 0, stream>>>(ab, wprojT, bproj, 8192, 2048, 2048,
                                      out, nullptr, nullptr, nullptr);
}

// Round 16
// 510.874 us; speedup vs baseline: 4.8009x; 1.0229x over previous
//
#include <hip/hip_runtime.h>

// ---------------------------------------------------------------------------
// Fused MHA: qkv = x@Wqkv+b ; causal attention ; out = attn@Wproj+b
// B=4, T=2048, C=2048, H=16, D=128. fp32 in/out, bf16 MFMA internally.
// GEMM = R8 256x256 + wave-parity phase offset (de-phase SIMD-mate waves).
// attn = R15 KVBLK=128 swapped-QK. transpose = vectorized 64x64.
// ---------------------------------------------------------------------------

typedef __bf16 bf16;
typedef __bf16 bf16x8 __attribute__((ext_vector_type(8)));
typedef __bf16 bf16x4 __attribute__((ext_vector_type(4)));
typedef float f32x4 __attribute__((ext_vector_type(4)));

__device__ __forceinline__ void gload_lds16(const void* g, void* l) {
  __builtin_amdgcn_global_load_lds(
      (const __attribute__((address_space(1))) void*)g,
      (__attribute__((address_space(3))) void*)l, 16, 0, 0);
}

// ---------------------------------------------------------------------------
// cast fp32 -> bf16, 8 elems/thread, grid-stride (G11: 2048 blocks)
__global__ __launch_bounds__(256) void cast_f32_bf16(
    const float* __restrict__ in, bf16* __restrict__ out, int n8) {
  for (int i = blockIdx.x * 256 + threadIdx.x; i < n8; i += gridDim.x * 256) {
    const float4* p = (const float4*)in + (size_t)i * 2;
    float4 a = p[0], b = p[1];
    bf16x8 o8 = {(bf16)a.x, (bf16)a.y, (bf16)a.z, (bf16)a.w,
                 (bf16)b.x, (bf16)b.y, (bf16)b.z, (bf16)b.w};
    *(bf16x8*)(out + (size_t)i * 8) = o8;
  }
}

// ---------------------------------------------------------------------------
// W [R][C] fp32 -> WT [C][R] bf16. 64x64 tile, 256 thr, vectorized (G13).
__global__ __launch_bounds__(256) void transpose_cast(
    const float* __restrict__ in, bf16* __restrict__ out, int R, int C) {
  __shared__ bf16 tile[64 * 64];  // 8 KB, swizzled
  const int r0 = blockIdx.y * 64, c0 = blockIdx.x * 64;
  const int t = threadIdx.x;
  const int ri = t >> 2, cseg = (t & 3) * 16;
  const float4* src =
      (const float4*)&in[(size_t)(r0 + ri) * C + c0 + cseg];
  float4 f0 = src[0], f1 = src[1], f2 = src[2], f3 = src[3];
  bf16x8 h0 = {(bf16)f0.x, (bf16)f0.y, (bf16)f0.z, (bf16)f0.w,
               (bf16)f1.x, (bf16)f1.y, (bf16)f1.z, (bf16)f1.w};
  bf16x8 h1 = {(bf16)f2.x, (bf16)f2.y, (bf16)f2.z, (bf16)f2.w,
               (bf16)f3.x, (bf16)f3.y, (bf16)f3.z, (bf16)f3.w};
  const int kx = (ri & 7) << 3;
  *(bf16x8*)&tile[ri * 64 + (cseg ^ kx)] = h0;
  *(bf16x8*)&tile[ri * 64 + ((cseg + 8) ^ kx)] = h1;
  __syncthreads();
  const int oj = t >> 2, rseg = (t & 3) * 16;
  bf16 v[16];
#pragma unroll
  for (int i = 0; i < 16; ++i) {
    const int rr = rseg + i;
    v[i] = tile[rr * 64 + (oj ^ ((rr & 7) << 3))];
  }
  bf16* dst = &out[(size_t)(c0 + oj) * R + r0 + rseg];
  *(bf16x8*)dst = *(bf16x8*)&v[0];
  *(bf16x8*)(dst + 8) = *(bf16x8*)&v[8];
}

// ---------------------------------------------------------------------------
// 256x256 GEMM (R8 structure) + WAVE-PARITY PHASE OFFSET: odd waves compute
// kh1 then kh0, even waves kh0 then kh1. SIMD-mate waves (phase-aligned at
// the barrier) then issue ds_read batches / MFMA bursts in opposite order,
// so one wave's matrix burst covers the other's lgkm wait (the ~3700 cy/tile
// unaccounted by MFMA+LDS throughput is coincident-stall serialization).
// Per-wave accumulate order changes only within the wave (fp-benign).
template <int EPI>
__global__ __launch_bounds__(512, 2) void gemm256(
    const bf16* __restrict__ A, const bf16* __restrict__ BT,
    const float* __restrict__ bias, int M, int N, int K,
    float* __restrict__ outf, bf16* __restrict__ qb, bf16* __restrict__ kb,
    bf16* __restrict__ vtb) {
  __shared__ bf16 As[2][2][256 * 32];  // 64 KB
  __shared__ bf16 Bs[2][2][256 * 32];  // 64 KB
  const int tid = threadIdx.x;
  const int lane = tid & 63, w = tid >> 6;
  const int wm = w >> 2, wn = w & 3;
  const int lr = lane & 15, lg = lane >> 4;

  // bijective XCD swizzle (gridDim.x % 8 == 0 for both instantiations)
  const int nwg = gridDim.x, cpx = nwg >> 3;
  const int swz = (blockIdx.x & 7) * cpx + (blockIdx.x >> 3);
  const int ntx = N >> 8;  // tiles along N
  const int m0 = (swz / ntx) * 256, n0 = (swz % ntx) * 256;

  // stage one 16KB half-tile (kh, operand) of K-tile kt into dbuf d.
  // dest linear; source col pre-XOR'd by row-bit3 (both-sides swizzle).
  auto STAGE_H = [&](int d, int skh, int sisB, int kt) {
    const bf16* src = sisB ? BT : A;
    const int r0 = sisB ? n0 : m0;
    bf16* lb = sisB ? &Bs[d][skh][0] : &As[d][skh][0];
#pragma unroll
    for (int c = 0; c < 2; ++c) {
      const int chunk = w * 2 + c;                    // 0..15 (1KB chunks)
      const int row = chunk * 16 + (lane >> 2);       // 0..255
      const int col = ((lane & 3) * 8) ^ (((row >> 3) & 1) << 4);
      gload_lds16(src + (size_t)(r0 + row) * K + kt * 64 + skh * 32 + col,
                  (char*)lb + chunk * 1024);
    }
  };
  // fragment reads (swizzled): logical (row, lg*8..+7) of K-half kh
  auto LDA = [&](int d, int kh, int mi) -> bf16x8 {
    const int row = wm * 128 + mi * 16 + lr;
    return *(const bf16x8*)((const char*)&As[d][kh][0] +
                            ((row * 64 + lg * 16) ^ ((lr >> 3) << 5)));
  };
  auto LDB = [&](int d, int kh, int ni) -> bf16x8 {
    const int row = wn * 64 + ni * 16 + lr;
    return *(const bf16x8*)((const char*)&Bs[d][kh][0] +
                            ((row * 64 + lg * 16) ^ ((lr >> 3) << 5)));
  };

  f32x4 acc[8][4] = {};
  const int NT = K >> 6;

  // one half-K compute: 12 ds_read + 32 MFMA, compiler-scheduled
  auto COMPUTE = [&](int d, int kh) {
    bf16x8 af[8], bfr[4];
#pragma unroll
    for (int mi = 0; mi < 8; ++mi) af[mi] = LDA(d, kh, mi);
#pragma unroll
    for (int ni = 0; ni < 4; ++ni) bfr[ni] = LDB(d, kh, ni);
#pragma unroll
    for (int mi = 0; mi < 8; ++mi)
#pragma unroll
      for (int ni = 0; ni < 4; ++ni)
        acc[mi][ni] = __builtin_amdgcn_mfma_f32_16x16x32_bf16(
            af[mi], bfr[ni], acc[mi][ni], 0, 0, 0);
  };

  // prologue: stage tile 0 fully, drain, sync
  STAGE_H(0, 0, 0, 0);
  STAGE_H(0, 0, 1, 0);
  STAGE_H(0, 1, 0, 0);
  STAGE_H(0, 1, 1, 0);
  asm volatile("s_waitcnt vmcnt(0)" ::: "memory");
  __builtin_amdgcn_s_barrier();

  const int kh_first = w & 1;  // de-phase SIMD-mate waves
  for (int t = 0; t < NT; ++t) {
    const int cur = t & 1;
    if (t + 1 < NT) {  // issue next tile's 8 loads; they fly under 64 MFMA
      STAGE_H(cur ^ 1, 0, 0, t + 1);
      STAGE_H(cur ^ 1, 0, 1, t + 1);
      STAGE_H(cur ^ 1, 1, 0, t + 1);
      STAGE_H(cur ^ 1, 1, 1, t + 1);
    }
    __builtin_amdgcn_s_setprio(1);
    COMPUTE(cur, kh_first);
    COMPUTE(cur, kh_first ^ 1);
    __builtin_amdgcn_s_setprio(0);
    asm volatile("s_waitcnt vmcnt(0)" ::: "memory");
    __builtin_amdgcn_s_barrier();  // buf cur free + t+1 data visible
  }

  // epilogue: C/D layout col=lane&15, row=(lane>>4)*4+r  [m89/m91]
#pragma unroll
  for (int mi = 0; mi < 8; ++mi) {
    const int mbase = m0 + wm * 128 + mi * 16 + lg * 4;
#pragma unroll
    for (int ni = 0; ni < 4; ++ni) {
      const int n = n0 + wn * 64 + ni * 16 + lr;
      const float bv = bias[n];
      if (EPI == 1) {
#pragma unroll
        for (int r = 0; r < 4; ++r)
          outf[(size_t)(mbase + r) * N + n] = acc[mi][ni][r] + bv;
      } else {
        const int which = n >> 11;           // 0=q 1=k 2=v
        const int cc = n & 2047, h = cc >> 7, dd = cc & 127;
        const int b = mbase >> 11, t0 = mbase & 2047;  // 4-row group never
        const int bh = b * 16 + h;                     // crosses b boundary
        if (which == 2) {
          bf16x4 pk;
#pragma unroll
          for (int r = 0; r < 4; ++r) pk[r] = (bf16)(acc[mi][ni][r] + bv);
          *(bf16x4*)&vtb[((size_t)bh * 128 + dd) * 2048 + t0] = pk;
        } else {
          bf16* dst = (which == 0) ? qb : kb;
#pragma unroll
          for (int r = 0; r < 4; ++r)
            dst[((size_t)bh * 2048 + t0 + r) * 128 + dd] =
                (bf16)(acc[mi][ni][r] + bv);
        }
      }
    }
  }
}

// ---------------------------------------------------------------------------
// Flash attention, causal, WORK-BALANCED pairing, SWAPPED QK^T, KVBLK=128.
// (R15 version, unchanged.)
__global__ __launch_bounds__(512) void attn_kernel(
    const bf16* __restrict__ qb, const bf16* __restrict__ kb,
    const bf16* __restrict__ vtb, bf16* __restrict__ ob) {
  __shared__ bf16 Ks[2][128 * 128];  // 64 KB, swizzled
  __shared__ bf16 Vs[2][128 * 128];  // 64 KB, swizzled ([d][t])
  __shared__ bf16 Ps[8][16 * 64];    // 16 KB, swizzled
  const int tid = threadIdx.x, lane = tid & 63, w = tid >> 6;
  const int bh = blockIdx.y;
  const int qtA = blockIdx.x;            // 0..7
  const int qtB = 15 - qtA;              // 8..15
  const int qt_w = (w < 4) ? qtA : qtB;  // this wave's q-tile
  const int wq = w & 3;                  // wave slot within its q-tile
  const int lr = lane & 15, lg = lane >> 4;
  const int q0 = qt_w * 128;
  const size_t base = (size_t)bh * (2048 * 128);
  const int rswz = (lr & 7) << 3;  // row-XOR (element domain)

  // hoist Q frags; fold (1/sqrt(D))*log2(e) so softmax runs in exp2 domain
  const float qscale = 0.08838834764831845f * 1.4426950408889634f;
  bf16x8 qf[2][4];
#pragma unroll
  for (int g = 0; g < 2; ++g) {
    const bf16* qp =
        qb + base + (size_t)(q0 + g * 64 + wq * 16 + lr) * 128 + lg * 8;
#pragma unroll
    for (int kk = 0; kk < 4; ++kk) {
      bf16x8 t = *(const bf16x8*)(qp + kk * 32);
#pragma unroll
      for (int e = 0; e < 8; ++e) t[e] = (bf16)((float)t[e] * qscale);
      qf[g][kk] = t;
    }
  }

  f32x4 o[2][8] = {};
  float mst[2] = {-1e30f, -1e30f};  // running max for q = lr (exp2 domain)
  float lst[2] = {0.f, 0.f};        // running sum for q = lr

  // stage 128-wide tile kt: K 32KB + V 32KB; 8 gload_lds/thread.
  auto STAGE = [&](int bsel, int kt) {
#pragma unroll
    for (int c = 0; c < 4; ++c) {
      const int off = w * 1024 + c * 8192 + lane * 16;  // byte off in 32KB
      const int row = off >> 8, ce = (off & 255) >> 1;  // 256B rows
      gload_lds16(kb + base + (size_t)(kt * 128 + row) * 128 +
                      (ce ^ ((row & 7) << 3)),
                  (char*)Ks[bsel] + w * 1024 + c * 8192);
      gload_lds16(vtb + base + (size_t)row * 2048 + kt * 128 +
                      (ce ^ ((row & 7) << 3)),
                  (char*)Vs[bsel] + w * 1024 + c * 8192);
    }
  };

  const int nst = qtB + 1;  // 128-wide tiles (covers A's range too)
  STAGE(0, 0);              // 8 outstanding
  for (int kt = 0; kt < nst; ++kt) {
    const int cur = kt & 1;
    if (kt + 1 < nst) {
      STAGE(cur ^ 1, kt + 1);  // 8 more in flight
      asm volatile("s_waitcnt vmcnt(8)" ::: "memory");  // tile kt landed
    } else {
      asm volatile("s_waitcnt vmcnt(0)" ::: "memory");
    }
    __builtin_amdgcn_s_barrier();  // all waves' staging of kt visible
    __builtin_amdgcn_sched_barrier(0);

    const bf16* Kc = Ks[cur];
    const bf16* Vc = Vs[cur];
#pragma unroll
    for (int g = 0; g < 2; ++g) {
      const int gb = 2 * qt_w + g;       // global 64-row q-group index
      const int gbrel = gb - 2 * kt;     // tile covers k-blocks 2kt,2kt+1
      if (gbrel < 0) continue;           // wave-uniform: past diagonal

      // S' = K Q^T (swapped): s[j], k_rel = j*16+lg*4+r (0..127), q = lr
      f32x4 s[8] = {};
      __builtin_amdgcn_s_setprio(1);
#pragma unroll
      for (int kk = 0; kk < 4; ++kk)
#pragma unroll
        for (int j = 0; j < 8; ++j) {
          const bf16x8 kf = *(const bf16x8*)&Kc[(j * 16 + lr) * 128 +
                                               ((kk * 32 + lg * 8) ^ rswz)];
          s[j] = __builtin_amdgcn_mfma_f32_16x16x32_bf16(kf, qf[g][kk], s[j],
                                                         0, 0, 0);
        }
      __builtin_amdgcn_s_setprio(0);

      if (gbrel <= 1) {  // diagonal lives in this tile
        const int qq = gbrel * 64 + wq * 16 + lr;  // diag threshold (k units)
#pragma unroll
        for (int j = 0; j < 8; ++j)
#pragma unroll
          for (int r = 0; r < 4; ++r)
            if (j * 16 + lg * 4 + r > qq) s[j][r] = -1e30f;
      }

      // in-lane softmax for q = lr (32 values in this lane)
      float pm;
      {
        float a0 = -1e30f, a1 = -1e30f;
#pragma unroll
        for (int j = 0; j < 8; j += 2) {
          a0 = fmaxf(a0, fmaxf(fmaxf(s[j][0], s[j][1]),
                               fmaxf(s[j][2], s[j][3])));
          a1 = fmaxf(a1, fmaxf(fmaxf(s[j + 1][0], s[j + 1][1]),
                               fmaxf(s[j + 1][2], s[j + 1][3])));
        }
        pm = fmaxf(a0, a1);
      }
      pm = fmaxf(pm, __shfl_xor(pm, 16));
      pm = fmaxf(pm, __shfl_xor(pm, 32));

      // T13 defer-max: rescale only when some row's max grew by >8
      if (__any(pm > mst[g] + 8.0f)) {
        const float mnew = fmaxf(mst[g], pm);
        const float alpha = __builtin_amdgcn_exp2f(mst[g] - mnew);
        mst[g] = mnew;
        lst[g] *= alpha;
#pragma unroll
        for (int r = 0; r < 4; ++r) {  // o rows: q = lg*4+r
          const float av = __shfl(alpha, (lane & 48) | (lg * 4 + r));
#pragma unroll
          for (int n = 0; n < 8; ++n) o[g][n][r] *= av;
        }
      }

      // P = exp2(s - m); in-lane sum + 2 shfl
      float rs = 0.f;
#pragma unroll
      for (int j = 0; j < 8; ++j)
#pragma unroll
        for (int r = 0; r < 4; ++r) {
          const float p = __builtin_amdgcn_exp2f(s[j][r] - mst[g]);
          s[j][r] = p;
          rs += p;
        }
      rs += __shfl_xor(rs, 16);
      rs += __shfl_xor(rs, 32);
      lst[g] += rs;

      // P @ V in two K=64 halves through the per-wave Ps buffer
      __builtin_amdgcn_s_setprio(1);
#pragma unroll
      for (int h = 0; h < 2; ++h) {
#pragma unroll
        for (int j2 = 0; j2 < 4; ++j2) {
          const int j = h * 4 + j2;
          bf16x4 pw;
#pragma unroll
          for (int r = 0; r < 4; ++r) pw[r] = (bf16)s[j][r];
          *(bf16x4*)&Ps[w][lr * 64 + ((j2 * 16 + lg * 4) ^ rswz)] = pw;
        }
        bf16x8 pf[2];
#pragma unroll
        for (int kk = 0; kk < 2; ++kk)
          pf[kk] = *(const bf16x8*)&Ps[w][lr * 64 +
                                         ((kk * 32 + lg * 8) ^ rswz)];
#pragma unroll
        for (int n = 0; n < 8; ++n)
#pragma unroll
          for (int kk = 0; kk < 2; ++kk) {
            const bf16x8 vf = *(const bf16x8*)&Vc[(n * 16 + lr) * 128 +
                                                 ((h * 64 + kk * 32 +
                                                   lg * 8) ^ rswz)];
            o[g][n] = __builtin_amdgcn_mfma_f32_16x16x32_bf16(
                pf[kk], vf, o[g][n], 0, 0, 0);
          }
      }
      __builtin_amdgcn_s_setprio(0);
    }
    __builtin_amdgcn_sched_barrier(0);
    __builtin_amdgcn_s_barrier();  // all reads of buf cur done before next
    __builtin_amdgcn_sched_barrier(0);  // STAGE overwrites it
  }

  // write attn-out as bf16 [B*T][C]; lst holds q=lr, o rows are q=lg*4+r
  const int b = bh >> 4, h = bh & 15;
#pragma unroll
  for (int g = 0; g < 2; ++g)
#pragma unroll
    for (int r = 0; r < 4; ++r) {
      const float inv = 1.0f / __shfl(lst[g], (lane & 48) | (lg * 4 + r));
      const int t = q0 + g * 64 + wq * 16 + lg * 4 + r;
      bf16* dst = ob + ((size_t)(b * 2048 + t)) * 2048 + h * 128;
#pragma unroll
      for (int n = 0; n < 8; ++n) dst[n * 16 + lr] = (bf16)(o[g][n][r] * inv);
    }
}

// ---------------------------------------------------------------------------
extern "C" void kernel_launch(void* const* d_in, const int* in_sizes, int n_in,
                              void* d_out, int out_size, void* d_ws,
                              size_t ws_size, hipStream_t stream) {
  const float* x = (const float*)d_in[0];      // [4,2048,2048]
  const float* Wqkv = (const float*)d_in[1];   // [2048,6144]
  const float* bqkv = (const float*)d_in[2];   // [6144]
  const float* Wproj = (const float*)d_in[3];  // [2048,2048]
  const float* bproj = (const float*)d_in[4];  // [2048]
  float* out = (float*)d_out;                  // [8192,2048] fp32

  char* ws = (char*)d_ws;  // needs ~192 MiB
  bf16* xb     = (bf16*)(ws);                  // 33554432 B  x bf16
  bf16* wqkvT  = (bf16*)(ws + 33554432);       // 25165824 B  Wqkv^T
  bf16* wprojT = (bf16*)(ws + 58720256);       //  8388608 B  Wproj^T
  bf16* qb     = (bf16*)(ws + 67108864);       // 33554432 B  Q [BH][T][D]
  bf16* kb     = (bf16*)(ws + 100663296);      // 33554432 B  K [BH][T][D]
  bf16* vtb    = (bf16*)(ws + 134217728);      // 33554432 B  V^T [BH][D][T]
  bf16* ab     = (bf16*)(ws + 167772160);      // 33554432 B  attn out bf16

  cast_f32_bf16<<<2048, 256, 0, stream>>>(x, xb, 2097152);
  transpose_cast<<<dim3(96, 32), 256, 0, stream>>>(Wqkv, wqkvT, 2048, 6144);
  transpose_cast<<<dim3(32, 32), 256, 0, stream>>>(Wproj, wprojT, 2048, 2048);
  gemm256<0><<<768, 512, 0, stream>>>(xb, wqkvT, bqkv, 8192, 6144, 2048,
                                      nullptr, qb, kb, vtb);
  attn_kernel<<<dim3(8, 64), 512, 0, stream>>>(qb, kb, vtb, ab);
  gemm256<1><<<256, 512, 0, stream>>>(ab, wprojT, bproj, 8192, 2048, 2048,
                                      out, nullptr, nullptr, nullptr);
}